// Round 1
// baseline (18006.186 us; speedup 1.0000x reference)
//
#include <hip/hip_runtime.h>
#include <math.h>

// ---------------- constants ----------------
#define L_LOC 12769              // 113*113 sliding-window positions
#define NB 2                     // batch
#define NLR (NB * L_LOC)         // 25538 total rows

enum { EP_LIN = 0, EP_RELU = 1, EP_SIG = 2, EP_SCALE = 3, EP_S = 4, EP_SOFT = 5, EP_XP = 6 };

__device__ __forceinline__ float softf(float x, float l) {
  float a = fmaxf(fabsf(x) - l, 0.0f);
  return x > 0.0f ? a : (x < 0.0f ? -a : 0.0f);
}
__device__ __forceinline__ float sigf(float x) { return 1.0f / (1.0f + expf(-x)); }

// ---------------- generic tiled fp32 GEMM ----------------
// C[m,n] = epi( sum_k A[m,k]*B[k,n] )
// TA: A stored [K x lda] accessed A[k*lda+m]   (A^T)
// TB: B stored [N x ldb] accessed B[n*ldb+k]   (B^T)
template <int TA, int TB, int EPI>
__global__ __launch_bounds__(256) void gemm_k(
    const float* __restrict__ A, int lda, const float* __restrict__ B, int ldb,
    float* __restrict__ C, int ldc, const float* __restrict__ bias,
    const float* __restrict__ E1, const float* __restrict__ E2, int lde,
    const float* __restrict__ cptr, int M, int N, int K)
{
  __shared__ float As[16][68];
  __shared__ float Bs[16][68];
  const int t = threadIdx.x;
  const int tx = t & 15, ty = t >> 4;
  const int m0 = blockIdx.x * 64, n0 = blockIdx.y * 64;
  float acc[4][4] = {};
  for (int k0 = 0; k0 < K; k0 += 16) {   // all K here are multiples of 16
#pragma unroll
    for (int r = 0; r < 4; ++r) {
      int li = t + 256 * r;
      int m, ka;
      if (TA) { ka = li >> 6; m = li & 63; } else { m = li >> 4; ka = li & 15; }
      float va = 0.0f;
      if (m0 + m < M) va = TA ? A[(size_t)(k0 + ka) * lda + (m0 + m)]
                              : A[(size_t)(m0 + m) * lda + (k0 + ka)];
      As[ka][m] = va;
      int n, kb;
      if (TB) { n = li >> 4; kb = li & 15; } else { kb = li >> 6; n = li & 63; }
      float vb = 0.0f;
      if (n0 + n < N) vb = TB ? B[(size_t)(n0 + n) * ldb + (k0 + kb)]
                              : B[(size_t)(k0 + kb) * ldb + (n0 + n)];
      Bs[kb][n] = vb;
    }
    __syncthreads();
#pragma unroll
    for (int kk = 0; kk < 16; ++kk) {
      float4 av = *(const float4*)&As[kk][ty * 4];
      float4 bv = *(const float4*)&Bs[kk][tx * 4];
      float a_[4] = {av.x, av.y, av.z, av.w};
      float b_[4] = {bv.x, bv.y, bv.z, bv.w};
#pragma unroll
      for (int i = 0; i < 4; ++i)
#pragma unroll
        for (int j = 0; j < 4; ++j) acc[i][j] = fmaf(a_[i], b_[j], acc[i][j]);
    }
    __syncthreads();
  }
  float invc = 1.0f;
  if (EPI == EP_SCALE || EPI == EP_S || EPI == EP_SOFT) invc = 1.0f / cptr[0];
#pragma unroll
  for (int i = 0; i < 4; ++i) {
    int m = m0 + ty * 4 + i;
    if (m >= M) continue;
#pragma unroll
    for (int j = 0; j < 4; ++j) {
      int n = n0 + tx * 4 + j;
      if (n >= N) continue;
      float v = acc[i][j];
      if (EPI == EP_LIN || EPI == EP_RELU || EPI == EP_SIG || EPI == EP_SCALE)
        if (bias) v += bias[n];
      if (EPI == EP_RELU) v = fmaxf(v, 0.0f);
      if (EPI == EP_SIG) v = sigf(v);
      if (EPI == EP_SCALE) v *= invc;
      if (EPI == EP_S) v = (m == n ? 1.0f : 0.0f) - v * invc;
      if (EPI == EP_SOFT) {
        size_t e = (size_t)m * lde + n;
        v = softf(v + E1[e] * invc, E2[e]);
      }
      if (EPI == EP_XP) {
        size_t e = (size_t)m * lde + n;
        v = fminf(fmaxf(v, 0.0f), 1.0f) * E1[e];
      }
      C[(size_t)m * ldc + n] = v;
    }
  }
}

static void gemm(hipStream_t st, int TA, int TB, int EPI,
                 const float* A, int lda, const float* B, int ldb,
                 float* C, int ldc, const float* bias,
                 const float* E1, const float* E2, int lde,
                 const float* cptr, int M, int N, int K)
{
  dim3 grid((M + 63) / 64, (N + 63) / 64), blk(256);
#define GEMM_GO(ta, tb, ep) gemm_k<ta, tb, ep><<<grid, blk, 0, st>>>(A, lda, B, ldb, C, ldc, bias, E1, E2, lde, cptr, M, N, K)
  if (TA == 1)      { GEMM_GO(1, 0, EP_S); }
  else if (TB == 1) { GEMM_GO(0, 1, EP_XP); }
  else switch (EPI) {
    case EP_LIN:   GEMM_GO(0, 0, EP_LIN); break;
    case EP_RELU:  GEMM_GO(0, 0, EP_RELU); break;
    case EP_SIG:   GEMM_GO(0, 0, EP_SIG); break;
    case EP_SCALE: GEMM_GO(0, 0, EP_SCALE); break;
    case EP_SOFT:  GEMM_GO(0, 0, EP_SOFT); break;
  }
#undef GEMM_GO
}

// ---------------- small kernels ----------------
// uf[rl,p] = img[(i0+kh)*128 + j0+kw], l = r0+rl, p = kh*16+kw
__global__ void unfold_k(const float* __restrict__ img, float* __restrict__ uf, int r0) {
  int idx = blockIdx.x * 256 + threadIdx.x;
  int rl = idx >> 8, p = idx & 255;
  int l = r0 + rl;
  int i0 = l / 113, j0 = l - i0 * 113;
  int kh = p >> 4, kw = p & 15;
  uf[idx] = img[(i0 + kh) * 128 + j0 + kw];
}

// ext[n,e,p]: stride-8 unfold rows l1 = 2e (e<112)
__global__ void ext_k(const float* __restrict__ x, float* __restrict__ ext) {
  int idx = blockIdx.x * 256 + threadIdx.x;  // 2*112*256
  int p = idx & 255;
  int t2 = idx >> 8;
  int e = t2 % 112, n = t2 / 112;
  int l1 = 2 * e;
  int i1 = l1 / 15, j1 = l1 % 15;
  int kh = p >> 4, kw = p & 15;
  ext[idx] = x[n * 16384 + (8 * i1 + kh) * 128 + 8 * j1 + kw];
}

__global__ void rownorm_k(float* sd) {
  int r = blockIdx.x * 64 + threadIdx.x;
  if (r >= 224) return;
  float s = 0.0f;
  for (int i = 0; i < 256; ++i) { float v = sd[r * 256 + i]; s += v * v; }
  float sc = 1.0f / fmaxf(sqrtf(s), 1e-12f);
  for (int i = 0; i < 256; ++i) sd[r * 256 + i] *= sc;
}

// channel mean/max over the 112 spatial positions  (x_cb[n,ch,s] = sd[n,s,ch])
__global__ void meanmax_k(const float* __restrict__ sd, float* mv, float* xv) {
  int id = blockIdx.x * 256 + threadIdx.x;  // 512
  if (id >= 512) return;
  int n = id >> 8, ch = id & 255;
  float s = 0.0f, m = -INFINITY;
  for (int e = 0; e < 112; ++e) {
    float v = sd[(n * 112 + e) * 256 + ch];
    s += v; m = fmaxf(m, v);
  }
  mv[id] = s * (1.0f / 112.0f);
  xv[id] = m;
}

__global__ void ca_h_k(const float* __restrict__ mv, const float* __restrict__ xv,
                       const float* __restrict__ w1, float* hm, float* hx) {
  int id = blockIdx.x * 256 + threadIdx.x;  // 2*512
  if (id >= 1024) return;
  int n = id >> 9, o = id & 511;
  float sm = 0.0f, sx = 0.0f;
  for (int i = 0; i < 256; ++i) {
    float w = w1[i * 512 + o];
    sm += mv[n * 256 + i] * w;
    sx += xv[n * 256 + i] * w;
  }
  hm[id] = fmaxf(sm, 0.0f);
  hx[id] = fmaxf(sx, 0.0f);
}

__global__ void ca_o_k(const float* __restrict__ hm, const float* __restrict__ hx,
                       const float* __restrict__ w2, float* ca) {
  int id = blockIdx.x * 256 + threadIdx.x;  // 512
  if (id >= 512) return;
  int n = id >> 8, ch = id & 255;
  float s = 0.0f;
  for (int o = 0; o < 512; ++o) s += (hm[n * 512 + o] + hx[n * 512 + o]) * w2[o * 256 + ch];
  ca[id] = sigf(s);
}

// apply channel attention, write sd-part of Dcat, compute spatial mean/max over channels
__global__ void chatt_k(const float* __restrict__ sd, const float* __restrict__ ca,
                        float* __restrict__ Dcat, float* smean, float* smax) {
  int id = blockIdx.x * 256 + threadIdx.x;  // 224
  if (id >= 224) return;
  int n = id / 112, s = id % 112;
  float sum = 0.0f, mx = -INFINITY;
  for (int ch = 0; ch < 256; ++ch) {
    float v = sd[(n * 112 + s) * 256 + ch] * ca[n * 256 + ch];
    Dcat[(size_t)n * 159744 + ch * 624 + 512 + s] = v;
    sum += v; mx = fmaxf(mx, v);
  }
  smean[id] = sum * (1.0f / 256.0f);
  smax[id] = mx;
}

// 7x7 spatial-attention conv (pad 3) + scale Dcat sd-part
__global__ void convsa_k(const float* __restrict__ smean, const float* __restrict__ smax,
                         const float* __restrict__ saw, float* __restrict__ Dcat) {
  int id = blockIdx.x * 256 + threadIdx.x;  // 224
  if (id >= 224) return;
  int n = id / 112, s = id % 112;
  int h = s / 14, w = s % 14;
  float acc = 0.0f;
  for (int dh = 0; dh < 7; ++dh) {
    int hh = h + dh - 3; if (hh < 0 || hh >= 8) continue;
    for (int dw = 0; dw < 7; ++dw) {
      int ww = w + dw - 3; if (ww < 0 || ww >= 14) continue;
      int sp = hh * 14 + ww;
      acc += smean[n * 112 + sp] * saw[dh * 7 + dw] + smax[n * 112 + sp] * saw[49 + dh * 7 + dw];
    }
  }
  float sg = sigf(acc);
  for (int ch = 0; ch < 256; ++ch) Dcat[(size_t)n * 159744 + ch * 624 + 512 + s] *= sg;
}

__global__ void dictfill_k(const float* __restrict__ Dict, float* __restrict__ Dcat) {
  int idx = blockIdx.x * 256 + threadIdx.x;  // 2*256*512
  if (idx >= 262144) return;
  int n = idx / 131072, r = idx % 131072;
  int p = r >> 9, a = r & 511;
  Dcat[(size_t)n * 159744 + p * 624 + a] = Dict[r];
}

__global__ void softinit_k(const float* __restrict__ y, const float* __restrict__ thr,
                           float* __restrict__ z, int cnt) {
  int idx = blockIdx.x * 256 + threadIdx.x;
  if (idx < cnt) z[idx] = softf(y[idx], thr[idx]);
}

// overlap-add fold of xp and wg, then divide (pure gather)
__global__ void folddiv_k(const float* __restrict__ xp, const float* __restrict__ wg,
                          float* __restrict__ out) {
  int idx = blockIdx.x * 256 + threadIdx.x;  // 2*128*128
  if (idx >= 32768) return;
  int n = idx >> 14, rem = idx & 16383;
  int i = rem >> 7, j = rem & 127;
  float num = 0.0f, den = 0.0f;
  int kh0 = (i - 112 > 0) ? i - 112 : 0;
  int kh1 = (i < 15) ? i : 15;
  int kw0 = (j - 112 > 0) ? j - 112 : 0;
  int kw1 = (j < 15) ? j : 15;
  for (int kh = kh0; kh <= kh1; ++kh)
    for (int kw = kw0; kw <= kw1; ++kw) {
      int l = (i - kh) * 113 + (j - kw);
      size_t base = ((size_t)(n * L_LOC + l)) * 256 + kh * 16 + kw;
      num += xp[base];
      den += wg[base];
    }
  out[idx] = num / den;
}

// ---------------- host orchestration ----------------
struct StageBufs {
  float *xp, *wg, *Dcat, *S, *ext, *sb1, *sb2, *sd;
  float *mv, *xv, *hm, *hx, *ca, *smean, *smax;
  float *uf, *h1, *h2, *thr, *y, *z, *zn;
  int R;
};

static void run_stage(hipStream_t st, const float* const* in, const float* img,
                      float* outimg, int pd0, int lam0, const StageBufs& b)
{
  const float* Dict = in[1];
  const float* cptr = in[2];
  // --- adaptive dictionary (sd) pipeline ---
  ext_k<<<dim3(224), dim3(256), 0, st>>>(img, b.ext);
  gemm(st, 0, 0, EP_RELU, b.ext, 256, in[3], 512, b.sb1, 512, in[4], 0, 0, 0, cptr, 224, 512, 256);
  gemm(st, 0, 0, EP_RELU, b.sb1, 512, in[5], 1024, b.sb2, 1024, in[6], 0, 0, 0, cptr, 224, 1024, 512);
  gemm(st, 0, 0, EP_RELU, b.sb2, 1024, in[7], 512, b.sb1, 512, in[8], 0, 0, 0, cptr, 224, 512, 1024);
  gemm(st, 0, 0, EP_LIN, b.sb1, 512, in[9], 256, b.sd, 256, in[10], 0, 0, 0, cptr, 224, 256, 512);
  rownorm_k<<<dim3(4), dim3(64), 0, st>>>(b.sd);
  meanmax_k<<<dim3(2), dim3(256), 0, st>>>(b.sd, b.mv, b.xv);
  ca_h_k<<<dim3(4), dim3(256), 0, st>>>(b.mv, b.xv, in[41], b.hm, b.hx);
  ca_o_k<<<dim3(2), dim3(256), 0, st>>>(b.hm, b.hx, in[42], b.ca);
  chatt_k<<<dim3(1), dim3(256), 0, st>>>(b.sd, b.ca, b.Dcat, b.smean, b.smax);
  convsa_k<<<dim3(1), dim3(256), 0, st>>>(b.smean, b.smax, in[43], b.Dcat);
  dictfill_k<<<dim3(1024), dim3(256), 0, st>>>(Dict, b.Dcat);
  // --- S = I - Dcat^T Dcat / c (per batch) ---
  for (int n = 0; n < NB; ++n) {
    const float* Dn = b.Dcat + (size_t)n * 159744;
    float* Sn = b.S + (size_t)n * 389376;
    gemm(st, 1, 0, EP_S, Dn, 624, Dn, 624, Sn, 624, 0, 0, 0, 0, cptr, 624, 624, 256);
  }
  // --- per-batch, per-row-chunk pipeline ---
  for (int n = 0; n < NB; ++n) {
    const float* imgn = img + n * 16384;
    const float* Dn = b.Dcat + (size_t)n * 159744;
    const float* Sn = b.S + (size_t)n * 389376;
    for (int r0 = 0; r0 < L_LOC; r0 += b.R) {
      int Rc = L_LOC - r0; if (Rc > b.R) Rc = b.R;
      unfold_k<<<dim3(Rc), dim3(256), 0, st>>>(imgn, b.uf, r0);
      // pd MLP -> thr[:, 0:512]
      gemm(st, 0, 0, EP_RELU, b.uf, 256, in[pd0], 1024, b.h1, 1024, in[pd0 + 1], 0, 0, 0, cptr, Rc, 1024, 256);
      gemm(st, 0, 0, EP_RELU, b.h1, 1024, in[pd0 + 2], 512, b.h2, 512, in[pd0 + 3], 0, 0, 0, cptr, Rc, 512, 1024);
      gemm(st, 0, 0, EP_SCALE, b.h2, 512, in[pd0 + 4], 512, b.thr, 624, in[pd0 + 5], 0, 0, 0, cptr, Rc, 512, 512);
      // lam MLP -> thr[:, 512:624]
      gemm(st, 0, 0, EP_RELU, b.uf, 256, in[lam0], 1024, b.h1, 1024, in[lam0 + 1], 0, 0, 0, cptr, Rc, 1024, 256);
      gemm(st, 0, 0, EP_RELU, b.h1, 1024, in[lam0 + 2], 512, b.h2, 512, in[lam0 + 3], 0, 0, 0, cptr, Rc, 512, 1024);
      gemm(st, 0, 0, EP_SCALE, b.h2, 512, in[lam0 + 4], 112, b.thr + 512, 624, in[lam0 + 5], 0, 0, 0, cptr, Rc, 112, 512);
      // w MLP -> Wg (sigmoid)
      float* wgp = b.wg + ((size_t)(n * L_LOC + r0)) * 256;
      gemm(st, 0, 0, EP_RELU, b.uf, 256, in[35], 1024, b.h1, 1024, in[36], 0, 0, 0, cptr, Rc, 1024, 256);
      gemm(st, 0, 0, EP_RELU, b.h1, 1024, in[37], 512, b.h2, 512, in[38], 0, 0, 0, cptr, Rc, 512, 1024);
      gemm(st, 0, 0, EP_SIG, b.h2, 512, in[39], 256, wgp, 256, in[40], 0, 0, 0, cptr, Rc, 256, 512);
      // y = uf @ Dcat_n
      gemm(st, 0, 0, EP_LIN, b.uf, 256, Dn, 624, b.y, 624, 0, 0, 0, 0, cptr, Rc, 624, 256);
      int tot = Rc * 624;
      softinit_k<<<dim3((tot + 255) / 256), dim3(256), 0, st>>>(b.y, b.thr, b.z, tot);
      // LISTA iterations
      float* zi = b.z; float* zo = b.zn;
      for (int it = 0; it < 5; ++it) {
        gemm(st, 0, 0, EP_SOFT, zi, 624, Sn, 624, zo, 624, 0, b.y, b.thr, 624, cptr, Rc, 624, 624);
        float* tmp = zi; zi = zo; zo = tmp;
      }
      // x_pred = clip(z @ Dcat^T, 0, 1) * Wg
      float* xpp = b.xp + ((size_t)(n * L_LOC + r0)) * 256;
      gemm(st, 0, 1, EP_XP, zi, 624, Dn, 624, xpp, 256, 0, wgp, 0, 256, cptr, Rc, 256, 624);
    }
  }
  folddiv_k<<<dim3(128), dim3(256), 0, st>>>(b.xp, b.wg, outimg);
}

extern "C" void kernel_launch(void* const* d_in, const int* in_sizes, int n_in,
                              void* d_out, int out_size, void* d_ws, size_t ws_size,
                              hipStream_t stream)
{
  (void)in_sizes; (void)n_in; (void)out_size;
  const float* const* in = (const float* const*)d_in;
  char* base = (char*)d_ws;
  size_t off = 0;
  auto alloc = [&](size_t nelem) -> float* {
    float* p = (float*)(base + off);
    off += ((nelem * sizeof(float) + 255) / 256) * 256;
    return p;
  };
  StageBufs b;
  b.xp = alloc((size_t)NLR * 256);
  b.wg = alloc((size_t)NLR * 256);
  b.Dcat = alloc(2 * 256 * 624);
  b.S = alloc(2 * 624 * 624);
  b.ext = alloc(224 * 256);
  b.sb1 = alloc(224 * 1024);
  b.sb2 = alloc(224 * 1024);
  b.sd = alloc(224 * 256);
  b.mv = alloc(512); b.xv = alloc(512);
  b.hm = alloc(1024); b.hx = alloc(1024);
  b.ca = alloc(512);
  b.smean = alloc(224); b.smax = alloc(224);
  float* res = alloc(2 * 16384);
  // row-chunk size adapted to remaining workspace
  long long avail = (long long)ws_size - (long long)off - 65536;
  long long perrow = 4288LL * 4 + 32;  // uf+h1+h2+thr+y+z+zn per row (+ align slack)
  long long Rll = avail > 0 ? avail / perrow : 0;
  int R = (Rll > L_LOC) ? L_LOC : (int)Rll;
  if (R < 64) R = 64;
  b.R = R;
  b.uf = alloc((size_t)R * 256);
  b.h1 = alloc((size_t)R * 1024);
  b.h2 = alloc((size_t)R * 512);
  b.thr = alloc((size_t)R * 624);
  b.y = alloc((size_t)R * 624);
  b.z = alloc((size_t)R * 624);
  b.zn = alloc((size_t)R * 624);

  // stage 1: pd = p* (idx 17), lam = a* (idx 11); stage 2: pd = q* (29), lam = b* (23)
  run_stage(stream, in, in[0], res, 17, 11, b);
  run_stage(stream, in, res, (float*)d_out, 29, 23, b);
}

// Round 3
// 7222.160 us; speedup vs baseline: 2.4932x; 2.4932x over previous
//
#include <hip/hip_runtime.h>
#include <hip/hip_bf16.h>
#include <math.h>

#define L_LOC 12769              // 113*113 sliding-window positions
#define NB 2
#define NLR (NB * L_LOC)

typedef short short8v __attribute__((ext_vector_type(8)));
typedef float f32x4 __attribute__((ext_vector_type(4)));
typedef __hip_bfloat16 bf16;

__device__ __forceinline__ float softf(float x, float l) {
  float a = fmaxf(fabsf(x) - l, 0.0f);
  return x > 0.0f ? a : (x < 0.0f ? -a : 0.0f);
}
__device__ __forceinline__ float sigf(float x) { return 1.0f / (1.0f + expf(-x)); }
__device__ __forceinline__ void split2(float v, bf16& h, bf16& l) {
  h = __float2bfloat16(v);
  l = __float2bfloat16(v - __bfloat162float(h));
}

// ================= fp32 SIMT GEMM (small matrices: sd pipeline, S build) =======
enum { EP_LIN = 0, EP_RELU = 1, EP_S = 4 };

template <int TA, int EPI>
__global__ __launch_bounds__(256) void gemm_k(
    const float* __restrict__ A, int lda, const float* __restrict__ B, int ldb,
    float* __restrict__ C, int ldc, const float* __restrict__ bias,
    const float* __restrict__ cptr, int M, int N, int K)
{
  __shared__ float As[16][68];
  __shared__ float Bs[16][68];
  const int t = threadIdx.x;
  const int tx = t & 15, ty = t >> 4;
  const int m0 = blockIdx.x * 64, n0 = blockIdx.y * 64;
  float acc[4][4] = {};
  for (int k0 = 0; k0 < K; k0 += 16) {
#pragma unroll
    for (int r = 0; r < 4; ++r) {
      int li = t + 256 * r;
      int m, ka;
      if (TA) { ka = li >> 6; m = li & 63; } else { m = li >> 4; ka = li & 15; }
      float va = 0.0f;
      if (m0 + m < M) va = TA ? A[(size_t)(k0 + ka) * lda + (m0 + m)]
                              : A[(size_t)(m0 + m) * lda + (k0 + ka)];
      As[ka][m] = va;
      int n = li & 63, kb = li >> 6;
      float vb = 0.0f;
      if (n0 + n < N) vb = B[(size_t)(k0 + kb) * ldb + (n0 + n)];
      Bs[kb][n] = vb;
    }
    __syncthreads();
#pragma unroll
    for (int kk = 0; kk < 16; ++kk) {
      float4 av = *(const float4*)&As[kk][ty * 4];
      float4 bv = *(const float4*)&Bs[kk][tx * 4];
      float a_[4] = {av.x, av.y, av.z, av.w};
      float b_[4] = {bv.x, bv.y, bv.z, bv.w};
#pragma unroll
      for (int i = 0; i < 4; ++i)
#pragma unroll
        for (int j = 0; j < 4; ++j) acc[i][j] = fmaf(a_[i], b_[j], acc[i][j]);
    }
    __syncthreads();
  }
  float invc = (EPI == EP_S) ? 1.0f / cptr[0] : 1.0f;
#pragma unroll
  for (int i = 0; i < 4; ++i) {
    int m = m0 + ty * 4 + i;
    if (m >= M) continue;
#pragma unroll
    for (int j = 0; j < 4; ++j) {
      int n = n0 + tx * 4 + j;
      if (n >= N) continue;
      float v = acc[i][j];
      if (EPI == EP_LIN || EPI == EP_RELU) { if (bias) v += bias[n]; }
      if (EPI == EP_RELU) v = fmaxf(v, 0.0f);
      if (EPI == EP_S) v = (m == n ? 1.0f : 0.0f) - v * invc;
      C[(size_t)m * ldc + n] = v;
    }
  }
}

static void gemm32(hipStream_t st, int TA, int EPI,
                   const float* A, int lda, const float* B, int ldb,
                   float* C, int ldc, const float* bias,
                   const float* cptr, int M, int N, int K)
{
  dim3 grid((M + 63) / 64, (N + 63) / 64), blk(256);
  if (TA)                  gemm_k<1, EP_S><<<grid, blk, 0, st>>>(A, lda, B, ldb, C, ldc, bias, cptr, M, N, K);
  else if (EPI == EP_RELU) gemm_k<0, EP_RELU><<<grid, blk, 0, st>>>(A, lda, B, ldb, C, ldc, bias, cptr, M, N, K);
  else                     gemm_k<0, EP_LIN><<<grid, blk, 0, st>>>(A, lda, B, ldb, C, ldc, bias, cptr, M, N, K);
}

// ================= split-bf16 MFMA GEMM ========================================
// A stored as two planes (hi at A, lo at A+aOff), each [Mpad][lda] bf16.
// Bt likewise (hi/lo planes of size bOff), [Npad][ldb] bf16 (pre-transposed).
// C[m,n] = epi( sum_k A[m,k]*Bt[n,k] ) with A*B ~= Ah*Bh + Ah*Bl + Al*Bh.
enum { ME_RELU = 0, ME_SCALE = 1, ME_SIG = 2, ME_Y = 3, ME_SOFT = 4, ME_XP = 5 };

template <int EPI>
__global__ __launch_bounds__(256) void mgemm_k(
    const bf16* __restrict__ A, int lda, size_t aOff,
    const bf16* __restrict__ Bt, int ldb, size_t bOff,
    void* __restrict__ Cv, int ldc, size_t cOff,
    const float* __restrict__ bias,
    const float* __restrict__ E1, const float* __restrict__ E2, int lde,
    const float* __restrict__ cptr, int Mv, int N, int K)
{
  __shared__ char As[2][8192];   // [hi/lo][128 rows][32 k] bf16
  __shared__ char Bs[2][8192];
  const int t = threadIdx.x;
  const int lane = t & 63, wv = t >> 6;
  const int wr = wv >> 1, wc = wv & 1;
  const int m0 = blockIdx.x * 128, n0 = blockIdx.y * 128;
  const int row16 = lane & 15, kg = lane >> 4;
  const int grow = t >> 2;          // 0..63 (row within 64-row half-tile)
  const int gcol = (t & 3) * 8;     // k element offset of this lane's 16B
  f32x4 acc[4][4];
#pragma unroll
  for (int i = 0; i < 4; ++i)
#pragma unroll
    for (int j = 0; j < 4; ++j) { acc[i][j][0] = 0.f; acc[i][j][1] = 0.f; acc[i][j][2] = 0.f; acc[i][j][3] = 0.f; }

  for (int k0 = 0; k0 < K; k0 += 32) {
#pragma unroll
    for (int h = 0; h < 2; ++h) {
#pragma unroll
      for (int i = 0; i < 2; ++i) {
        const bf16* ga = A + h * aOff + (size_t)(m0 + i * 64 + grow) * lda + k0 + gcol;
        __builtin_amdgcn_global_load_lds(
            (const __attribute__((address_space(1))) void*)ga,
            (__attribute__((address_space(3))) void*)(As[h] + i * 4096 + wv * 1024), 16, 0, 0);
        const bf16* gb = Bt + h * bOff + (size_t)(n0 + i * 64 + grow) * ldb + k0 + gcol;
        __builtin_amdgcn_global_load_lds(
            (const __attribute__((address_space(1))) void*)gb,
            (__attribute__((address_space(3))) void*)(Bs[h] + i * 4096 + wv * 1024), 16, 0, 0);
      }
    }
    __syncthreads();
    short8v ah[4], al[4], bh[4], bl[4];
#pragma unroll
    for (int mi = 0; mi < 4; ++mi) {
      int o = (wr * 64 + mi * 16 + row16) * 64 + kg * 16;
      ah[mi] = *(const short8v*)(As[0] + o);
      al[mi] = *(const short8v*)(As[1] + o);
    }
#pragma unroll
    for (int ni = 0; ni < 4; ++ni) {
      int o = (wc * 64 + ni * 16 + row16) * 64 + kg * 16;
      bh[ni] = *(const short8v*)(Bs[0] + o);
      bl[ni] = *(const short8v*)(Bs[1] + o);
    }
#pragma unroll
    for (int mi = 0; mi < 4; ++mi)
#pragma unroll
      for (int ni = 0; ni < 4; ++ni) {
        acc[mi][ni] = __builtin_amdgcn_mfma_f32_16x16x32_bf16(ah[mi], bl[ni], acc[mi][ni], 0, 0, 0);
        acc[mi][ni] = __builtin_amdgcn_mfma_f32_16x16x32_bf16(al[mi], bh[ni], acc[mi][ni], 0, 0, 0);
        acc[mi][ni] = __builtin_amdgcn_mfma_f32_16x16x32_bf16(ah[mi], bh[ni], acc[mi][ni], 0, 0, 0);
      }
    __syncthreads();
  }

  float invc = 1.0f;
  if (EPI == ME_SCALE || EPI == ME_SOFT) invc = 1.0f / cptr[0];
  bf16* Cb = (bf16*)Cv;
  float* Cf = (float*)Cv;
#pragma unroll
  for (int ni = 0; ni < 4; ++ni) {
    int col = n0 + wc * 64 + ni * 16 + row16;
    if (col >= N) continue;
    float bv = 0.0f;
    if (EPI == ME_RELU || EPI == ME_SCALE || EPI == ME_SIG) bv = bias[col];
#pragma unroll
    for (int mi = 0; mi < 4; ++mi) {
      int rowb = m0 + wr * 64 + mi * 16 + kg * 4;
#pragma unroll
      for (int r = 0; r < 4; ++r) {
        int row = rowb + r;
        if (row >= Mv) continue;
        float v = acc[mi][ni][r];
        size_t ci = (size_t)row * ldc + col;
        if (EPI == ME_RELU) {
          float o = fmaxf(v + bv, 0.0f);
          bf16 h, l; split2(o, h, l);
          Cb[ci] = h; Cb[ci + cOff] = l;
        } else if (EPI == ME_SCALE) {
          Cf[ci] = (v + bv) * invc;
        } else if (EPI == ME_SIG) {
          Cf[ci] = sigf(v + bv);
        } else if (EPI == ME_Y) {
          Cf[ci] = v;
        } else if (EPI == ME_SOFT) {
          size_t e = (size_t)row * lde + col;
          float o = softf(v + E1[e] * invc, E2[e]);
          bf16 h, l; split2(o, h, l);
          Cb[ci] = h; Cb[ci + cOff] = l;
        } else { // ME_XP
          size_t e = (size_t)row * lde + col;
          Cf[ci] = fminf(fmaxf(v, 0.0f), 1.0f) * E1[e];
        }
      }
    }
  }
}

static void mgemm(hipStream_t st, int EPI,
                  const bf16* A, int lda, size_t aOff,
                  const bf16* Bt, int ldb, size_t bOff,
                  void* C, int ldc, size_t cOff,
                  const float* bias, const float* E1, const float* E2,
                  int lde, const float* cptr, int Mv, int Mpad, int N, int K)
{
  dim3 grid(Mpad / 128, (N + 127) / 128), blk(256);
#define MG(ep) mgemm_k<ep><<<grid, blk, 0, st>>>(A, lda, aOff, Bt, ldb, bOff, C, ldc, cOff, bias, E1, E2, lde, cptr, Mv, N, K)
  switch (EPI) {
    case ME_RELU:  MG(ME_RELU); break;
    case ME_SCALE: MG(ME_SCALE); break;
    case ME_SIG:   MG(ME_SIG); break;
    case ME_Y:     MG(ME_Y); break;
    case ME_SOFT:  MG(ME_SOFT); break;
    case ME_XP:    MG(ME_XP); break;
  }
#undef MG
}

// ================= small kernels ==============================================
// weights: src fp32 [K][N] -> dst bf16 transposed [Np][Kp], hi plane + lo plane
__global__ void wtrans_k(const float* __restrict__ src, bf16* __restrict__ dst,
                         int K, int N, int Kp, int Np) {
  int idx = blockIdx.x * 256 + threadIdx.x;
  if (idx >= Np * Kp) return;
  int n = idx / Kp, k = idx - n * Kp;
  float v = (n < N && k < K) ? src[(size_t)k * N + n] : 0.0f;
  bf16 h, l; split2(v, h, l);
  dst[idx] = h; dst[idx + (size_t)Np * Kp] = l;
}

// Dcat fp32 [2][256][624] -> Db [n][2pl][256][640] and DbT [n][2pl][640][256]
__global__ void dcatconv_k(const float* __restrict__ Dc, bf16* __restrict__ Db,
                           bf16* __restrict__ DbT) {
  int idx = blockIdx.x * 256 + threadIdx.x;   // 2*256*640
  if (idx >= 327680) return;
  int n = idx / 163840, r = idx - n * 163840;
  int p = r / 640, a = r - p * 640;
  float v = (a < 624) ? Dc[(size_t)n * 159744 + p * 624 + a] : 0.0f;
  bf16 h, l; split2(v, h, l);
  size_t base = (size_t)n * 327680;
  Db[base + p * 640 + a] = h;
  Db[base + 163840 + p * 640 + a] = l;
  DbT[base + (size_t)a * 256 + p] = h;
  DbT[base + 163840 + (size_t)a * 256 + p] = l;
}

// S fp32 [2][624][624] -> Sb [n][2pl][640][640] zero-padded
__global__ void sconv_k(const float* __restrict__ Sf, bf16* __restrict__ Sb) {
  int idx = blockIdx.x * 256 + threadIdx.x;   // 2*640*640
  if (idx >= 819200) return;
  int n = idx / 409600, r = idx - n * 409600;
  int i = r / 640, j = r - i * 640;
  float v = (i < 624 && j < 624) ? Sf[(size_t)n * 389376 + i * 624 + j] : 0.0f;
  bf16 h, l; split2(v, h, l);
  size_t base = (size_t)n * 819200;
  Sb[base + r] = h; Sb[base + 409600 + r] = l;
}

__global__ void unfold_k(const float* __restrict__ img, bf16* __restrict__ uf,
                         int r0, size_t pOff) {
  int idx = blockIdx.x * 256 + threadIdx.x;
  int rl = idx >> 8, p = idx & 255;
  int l = r0 + rl;
  int i0 = l / 113, j0 = l - i0 * 113;
  int kh = p >> 4, kw = p & 15;
  float v = img[(i0 + kh) * 128 + j0 + kw];
  bf16 h, lo; split2(v, h, lo);
  uf[idx] = h; uf[idx + pOff] = lo;
}

__global__ void ext_k(const float* __restrict__ x, float* __restrict__ ext) {
  int idx = blockIdx.x * 256 + threadIdx.x;  // 2*112*256
  int p = idx & 255;
  int t2 = idx >> 8;
  int e = t2 % 112, n = t2 / 112;
  int l1 = 2 * e;
  int i1 = l1 / 15, j1 = l1 % 15;
  int kh = p >> 4, kw = p & 15;
  ext[idx] = x[n * 16384 + (8 * i1 + kh) * 128 + 8 * j1 + kw];
}

__global__ void rownorm_k(float* sd) {
  int r = blockIdx.x * 64 + threadIdx.x;
  if (r >= 224) return;
  float s = 0.0f;
  for (int i = 0; i < 256; ++i) { float v = sd[r * 256 + i]; s += v * v; }
  float sc = 1.0f / fmaxf(sqrtf(s), 1e-12f);
  for (int i = 0; i < 256; ++i) sd[r * 256 + i] *= sc;
}

__global__ void meanmax_k(const float* __restrict__ sd, float* mv, float* xv) {
  int id = blockIdx.x * 256 + threadIdx.x;
  if (id >= 512) return;
  int n = id >> 8, ch = id & 255;
  float s = 0.0f, m = -INFINITY;
  for (int e = 0; e < 112; ++e) {
    float v = sd[(n * 112 + e) * 256 + ch];
    s += v; m = fmaxf(m, v);
  }
  mv[id] = s * (1.0f / 112.0f);
  xv[id] = m;
}

__global__ void ca_h_k(const float* __restrict__ mv, const float* __restrict__ xv,
                       const float* __restrict__ w1, float* hm, float* hx) {
  int id = blockIdx.x * 256 + threadIdx.x;
  if (id >= 1024) return;
  int n = id >> 9, o = id & 511;
  float sm = 0.0f, sx = 0.0f;
  for (int i = 0; i < 256; ++i) {
    float w = w1[i * 512 + o];
    sm += mv[n * 256 + i] * w;
    sx += xv[n * 256 + i] * w;
  }
  hm[id] = fmaxf(sm, 0.0f);
  hx[id] = fmaxf(sx, 0.0f);
}

__global__ void ca_o_k(const float* __restrict__ hm, const float* __restrict__ hx,
                       const float* __restrict__ w2, float* ca) {
  int id = blockIdx.x * 256 + threadIdx.x;
  if (id >= 512) return;
  int n = id >> 8, ch = id & 255;
  float s = 0.0f;
  for (int o = 0; o < 512; ++o) s += (hm[n * 512 + o] + hx[n * 512 + o]) * w2[o * 256 + ch];
  ca[id] = sigf(s);
}

__global__ void chatt_k(const float* __restrict__ sd, const float* __restrict__ ca,
                        float* __restrict__ Dcat, float* smean, float* smax) {
  int id = blockIdx.x * 256 + threadIdx.x;
  if (id >= 224) return;
  int n = id / 112, s = id % 112;
  float sum = 0.0f, mx = -INFINITY;
  for (int ch = 0; ch < 256; ++ch) {
    float v = sd[(n * 112 + s) * 256 + ch] * ca[n * 256 + ch];
    Dcat[(size_t)n * 159744 + ch * 624 + 512 + s] = v;
    sum += v; mx = fmaxf(mx, v);
  }
  smean[id] = sum * (1.0f / 256.0f);
  smax[id] = mx;
}

__global__ void convsa_k(const float* __restrict__ smean, const float* __restrict__ smax,
                         const float* __restrict__ saw, float* __restrict__ Dcat) {
  int id = blockIdx.x * 256 + threadIdx.x;
  if (id >= 224) return;
  int n = id / 112, s = id % 112;
  int h = s / 14, w = s % 14;
  float acc = 0.0f;
  for (int dh = 0; dh < 7; ++dh) {
    int hh = h + dh - 3; if (hh < 0 || hh >= 8) continue;
    for (int dw = 0; dw < 7; ++dw) {
      int ww = w + dw - 3; if (ww < 0 || ww >= 14) continue;
      int sp = hh * 14 + ww;
      acc += smean[n * 112 + sp] * saw[dh * 7 + dw] + smax[n * 112 + sp] * saw[49 + dh * 7 + dw];
    }
  }
  float sg = sigf(acc);
  for (int ch = 0; ch < 256; ++ch) Dcat[(size_t)n * 159744 + ch * 624 + 512 + s] *= sg;
}

__global__ void dictfill_k(const float* __restrict__ Dict, float* __restrict__ Dcat) {
  int idx = blockIdx.x * 256 + threadIdx.x;  // 2*256*512
  if (idx >= 262144) return;
  int n = idx / 131072, r = idx % 131072;
  int p = r >> 9, a = r & 511;
  Dcat[(size_t)n * 159744 + p * 624 + a] = Dict[r];
}

__global__ void softinit_k(const float* __restrict__ y, const float* __restrict__ thr,
                           bf16* __restrict__ z, int Rc, size_t zOff) {
  int idx = blockIdx.x * 256 + threadIdx.x;
  if (idx >= Rc * 624) return;
  int row = idx / 624, col = idx - row * 624;
  size_t e = (size_t)row * 640 + col;
  float v = softf(y[e], thr[e]);
  bf16 h, l; split2(v, h, l);
  z[e] = h; z[e + zOff] = l;
}

__global__ void folddiv_k(const float* __restrict__ xp, const float* __restrict__ wg,
                          float* __restrict__ out) {
  int idx = blockIdx.x * 256 + threadIdx.x;
  if (idx >= 32768) return;
  int n = idx >> 14, rem = idx & 16383;
  int i = rem >> 7, j = rem & 127;
  float num = 0.0f, den = 0.0f;
  int kh0 = (i - 112 > 0) ? i - 112 : 0;
  int kh1 = (i < 15) ? i : 15;
  int kw0 = (j - 112 > 0) ? j - 112 : 0;
  int kw1 = (j < 15) ? j : 15;
  for (int kh = kh0; kh <= kh1; ++kh)
    for (int kw = kw0; kw <= kw1; ++kw) {
      int l = (i - kh) * 113 + (j - kw);
      size_t base = ((size_t)(n * L_LOC + l)) * 256 + kh * 16 + kw;
      num += xp[base];
      den += wg[base];
    }
  out[idx] = num / den;
}

// ================= host orchestration ==========================================
struct Bufs {
  float *xp, *wg, *Dcat_f, *S_f, *ext, *sb1, *sb2, *sd;
  float *mv, *xv, *hm, *hx, *ca, *smean, *smax, *res;
  bf16 *Db, *DbT, *Sb;
  bf16 *uf, *h1, *h2, *z, *zn;
  float *thr, *y;
  int R;
};

static void run_stage(hipStream_t st, const float* const* in, const float* img,
                      float* outimg, int pd0, int lam0,
                      bf16* const* WtPd, bf16* const* WtLam, bf16* const* WtW,
                      const Bufs& b)
{
  const float* Dict = in[1];
  const float* cptr = in[2];
  // --- adaptive dictionary pipeline (fp32, tiny) ---
  ext_k<<<dim3(224), dim3(256), 0, st>>>(img, b.ext);
  gemm32(st, 0, EP_RELU, b.ext, 256, in[3], 512, b.sb1, 512, in[4], cptr, 224, 512, 256);
  gemm32(st, 0, EP_RELU, b.sb1, 512, in[5], 1024, b.sb2, 1024, in[6], cptr, 224, 1024, 512);
  gemm32(st, 0, EP_RELU, b.sb2, 1024, in[7], 512, b.sb1, 512, in[8], cptr, 224, 512, 1024);
  gemm32(st, 0, EP_LIN, b.sb1, 512, in[9], 256, b.sd, 256, in[10], cptr, 224, 256, 512);
  rownorm_k<<<dim3(4), dim3(64), 0, st>>>(b.sd);
  meanmax_k<<<dim3(2), dim3(256), 0, st>>>(b.sd, b.mv, b.xv);
  ca_h_k<<<dim3(4), dim3(256), 0, st>>>(b.mv, b.xv, in[41], b.hm, b.hx);
  ca_o_k<<<dim3(2), dim3(256), 0, st>>>(b.hm, b.hx, in[42], b.ca);
  chatt_k<<<dim3(1), dim3(256), 0, st>>>(b.sd, b.ca, b.Dcat_f, b.smean, b.smax);
  convsa_k<<<dim3(1), dim3(256), 0, st>>>(b.smean, b.smax, in[43], b.Dcat_f);
  dictfill_k<<<dim3(1024), dim3(256), 0, st>>>(Dict, b.Dcat_f);
  // --- S = I - Dcat^T Dcat / c (fp32, exact), then split-convert ---
  for (int n = 0; n < NB; ++n)
    gemm32(st, 1, EP_S, b.Dcat_f + (size_t)n * 159744, 624, b.Dcat_f + (size_t)n * 159744, 624,
           b.S_f + (size_t)n * 389376, 624, 0, cptr, 624, 624, 256);
  dcatconv_k<<<dim3(1280), dim3(256), 0, st>>>(b.Dcat_f, b.Db, b.DbT);
  sconv_k<<<dim3(3200), dim3(256), 0, st>>>(b.S_f, b.Sb);

  const size_t ufO = (size_t)b.R * 256, h1O = (size_t)b.R * 1024;
  const size_t h2O = (size_t)b.R * 512, zO = (size_t)b.R * 640;
  // --- per-batch, per-chunk MFMA pipeline ---
  for (int n = 0; n < NB; ++n) {
    const float* imgn = img + n * 16384;
    const bf16* Dbn = b.Db + (size_t)n * 327680;
    const bf16* DbTn = b.DbT + (size_t)n * 327680;
    const bf16* Sbn = b.Sb + (size_t)n * 819200;
    for (int r0 = 0; r0 < L_LOC; r0 += b.R) {
      int Rc = L_LOC - r0; if (Rc > b.R) Rc = b.R;
      int Mp = ((Rc + 127) / 128) * 128;
      unfold_k<<<dim3(Rc), dim3(256), 0, st>>>(imgn, b.uf, r0, ufO);
      // pd MLP -> thr[:, :512]
      mgemm(st, ME_RELU, b.uf, 256, ufO, WtPd[0], 256, 1024 * 256, b.h1, 1024, h1O, in[pd0 + 1], 0, 0, 0, cptr, Rc, Mp, 1024, 256);
      mgemm(st, ME_RELU, b.h1, 1024, h1O, WtPd[1], 1024, 512 * 1024, b.h2, 512, h2O, in[pd0 + 3], 0, 0, 0, cptr, Rc, Mp, 512, 1024);
      mgemm(st, ME_SCALE, b.h2, 512, h2O, WtPd[2], 512, 512 * 512, b.thr, 640, 0, in[pd0 + 5], 0, 0, 0, cptr, Rc, Mp, 512, 512);
      // lam MLP -> thr[:, 512:624]
      mgemm(st, ME_RELU, b.uf, 256, ufO, WtLam[0], 256, 1024 * 256, b.h1, 1024, h1O, in[lam0 + 1], 0, 0, 0, cptr, Rc, Mp, 1024, 256);
      mgemm(st, ME_RELU, b.h1, 1024, h1O, WtLam[1], 1024, 512 * 1024, b.h2, 512, h2O, in[lam0 + 3], 0, 0, 0, cptr, Rc, Mp, 512, 1024);
      mgemm(st, ME_SCALE, b.h2, 512, h2O, WtLam[2], 512, 128 * 512, b.thr + 512, 640, 0, in[lam0 + 5], 0, 0, 0, cptr, Rc, Mp, 112, 512);
      // w MLP -> Wg (sigmoid, fp32)
      float* wgp = b.wg + ((size_t)(n * L_LOC + r0)) * 256;
      mgemm(st, ME_RELU, b.uf, 256, ufO, WtW[0], 256, 1024 * 256, b.h1, 1024, h1O, in[36], 0, 0, 0, cptr, Rc, Mp, 1024, 256);
      mgemm(st, ME_RELU, b.h1, 1024, h1O, WtW[1], 1024, 512 * 1024, b.h2, 512, h2O, in[38], 0, 0, 0, cptr, Rc, Mp, 512, 1024);
      mgemm(st, ME_SIG, b.h2, 512, h2O, WtW[2], 512, 256 * 512, wgp, 256, 0, in[40], 0, 0, 0, cptr, Rc, Mp, 256, 512);
      // y = uf @ Dcat
      mgemm(st, ME_Y, b.uf, 256, ufO, DbTn, 256, 163840, b.y, 640, 0, 0, 0, 0, 0, cptr, Rc, Mp, 624, 256);
      softinit_k<<<dim3((Rc * 624 + 255) / 256), dim3(256), 0, st>>>(b.y, b.thr, b.z, Rc, zO);
      // LISTA iterations
      bf16* zi = b.z; bf16* zo = b.zn;
      for (int it = 0; it < 5; ++it) {
        mgemm(st, ME_SOFT, zi, 640, zO, Sbn, 640, 409600, zo, 640, zO, 0, b.y, b.thr, 640, cptr, Rc, Mp, 624, 640);
        bf16* tmp = zi; zi = zo; zo = tmp;
      }
      // x_pred = clip(z @ Dcat^T, 0, 1) * Wg
      float* xpp = b.xp + ((size_t)(n * L_LOC + r0)) * 256;
      mgemm(st, ME_XP, zi, 640, zO, Dbn, 640, 163840, xpp, 256, 0, 0, wgp, 0, 256, cptr, Rc, Mp, 256, 640);
    }
  }
  folddiv_k<<<dim3(128), dim3(256), 0, st>>>(b.xp, b.wg, outimg);
}

extern "C" void kernel_launch(void* const* d_in, const int* in_sizes, int n_in,
                              void* d_out, int out_size, void* d_ws, size_t ws_size,
                              hipStream_t stream)
{
  (void)in_sizes; (void)n_in; (void)out_size;
  const float* const* in = (const float* const*)d_in;
  char* base = (char*)d_ws;
  size_t off = 0;
  auto allocf = [&](size_t nelem) -> float* {
    float* p = (float*)(base + off);
    off += ((nelem * 4 + 255) / 256) * 256;
    return p;
  };
  auto allocb = [&](size_t nelem) -> bf16* {   // nelem per plane, 2 planes
    bf16* p = (bf16*)(base + off);
    off += ((nelem * 2 * 2 + 255) / 256) * 256;
    return p;
  };
  Bufs b;
  b.xp = allocf((size_t)NLR * 256);
  b.wg = allocf((size_t)NLR * 256);
  b.Dcat_f = allocf(2 * 256 * 624);
  b.S_f = allocf(2 * 624 * 624);
  b.ext = allocf(224 * 256);
  b.sb1 = allocf(224 * 1024);
  b.sb2 = allocf(224 * 1024);
  b.sd = allocf(224 * 256);
  b.mv = allocf(512); b.xv = allocf(512);
  b.hm = allocf(1024); b.hx = allocf(1024);
  b.ca = allocf(512);
  b.smean = allocf(224); b.smax = allocf(224);
  b.res = allocf(2 * 16384);
  b.Db = allocb(2 * 256 * 640);
  b.DbT = allocb(2 * 640 * 256);
  b.Sb = allocb(2 * 640 * 640);

  // transposed split-bf16 weights
  bf16 *Wa[3], *Wp[3], *Wb[3], *Wq[3], *Ww[3];
  struct WDesc { bf16** slot; int inIdx; int K, N, Kp, Np; };
  WDesc wd[15] = {
    {&Wa[0], 11, 256, 1024, 256, 1024}, {&Wa[1], 13, 1024, 512, 1024, 512}, {&Wa[2], 15, 512, 112, 512, 128},
    {&Wp[0], 17, 256, 1024, 256, 1024}, {&Wp[1], 19, 1024, 512, 1024, 512}, {&Wp[2], 21, 512, 512, 512, 512},
    {&Wb[0], 23, 256, 1024, 256, 1024}, {&Wb[1], 25, 1024, 512, 1024, 512}, {&Wb[2], 27, 512, 112, 512, 128},
    {&Wq[0], 29, 256, 1024, 256, 1024}, {&Wq[1], 31, 1024, 512, 1024, 512}, {&Wq[2], 33, 512, 512, 512, 512},
    {&Ww[0], 35, 256, 1024, 256, 1024}, {&Ww[1], 37, 1024, 512, 1024, 512}, {&Ww[2], 39, 512, 256, 512, 256},
  };
  for (int i = 0; i < 15; ++i) {
    *wd[i].slot = allocb((size_t)wd[i].Np * wd[i].Kp);
    int tot = wd[i].Np * wd[i].Kp;
    wtrans_k<<<dim3((tot + 255) / 256), dim3(256), 0, stream>>>(
        in[wd[i].inIdx], *wd[i].slot, wd[i].K, wd[i].N, wd[i].Kp, wd[i].Np);
  }

  // chunk size: per-row bytes = bf16 split (256+1024+512+640+640)*2pl*2B = 12288
  //             + f32 (640+640)*4 = 5120  -> 17408 (+slack)
  long long avail = (long long)ws_size - (long long)off - (1 << 20);
  long long perrow = 17408 + 64;
  int R = 12800;
  if (avail / perrow < 12800) R = (int)(avail / perrow);
  R &= ~127;
  if (R < 128) R = 128;
  b.R = R;
  b.uf = allocb((size_t)R * 256);
  b.h1 = allocb((size_t)R * 1024);
  b.h2 = allocb((size_t)R * 512);
  b.z = allocb((size_t)R * 640);
  b.zn = allocb((size_t)R * 640);
  b.thr = allocf((size_t)R * 640);
  b.y = allocf((size_t)R * 640);

  // stage 1: pd = p*(17), lam = a*(11); stage 2: pd = q*(29), lam = b*(23)
  run_stage(stream, in, in[0], b.res, 17, 11, Wp, Wa, Ww, b);
  run_stage(stream, in, b.res, (float*)d_out, 29, 23, Wq, Wb, Ww, b);
}

// Round 4
// 5398.236 us; speedup vs baseline: 3.3356x; 1.3379x over previous
//
#include <hip/hip_runtime.h>
#include <hip/hip_bf16.h>
#include <math.h>

#define L_LOC 12769              // 113*113 sliding-window positions
#define NB 2
#define NLR (NB * L_LOC)

typedef short short8v __attribute__((ext_vector_type(8)));
typedef float f32x4 __attribute__((ext_vector_type(4)));
typedef __hip_bfloat16 bf16;

__device__ __forceinline__ float softf(float x, float l) {
  float a = fmaxf(fabsf(x) - l, 0.0f);
  return x > 0.0f ? a : (x < 0.0f ? -a : 0.0f);
}
__device__ __forceinline__ float sigf(float x) { return 1.0f / (1.0f + expf(-x)); }
__device__ __forceinline__ void split2(float v, bf16& h, bf16& l) {
  h = __float2bfloat16(v);
  l = __float2bfloat16(v - __bfloat162float(h));
}

// ================= fp32 SIMT GEMM (sd pipeline only, M=224) ====================
enum { EP_LIN = 0, EP_RELU = 1 };

template <int EPI>
__global__ __launch_bounds__(256) void gemm_k(
    const float* __restrict__ A, int lda, const float* __restrict__ B, int ldb,
    float* __restrict__ C, int ldc, const float* __restrict__ bias,
    int M, int N, int K)
{
  __shared__ float As[16][68];
  __shared__ float Bs[16][68];
  const int t = threadIdx.x;
  const int tx = t & 15, ty = t >> 4;
  const int m0 = blockIdx.x * 64, n0 = blockIdx.y * 64;
  float acc[4][4] = {};
  for (int k0 = 0; k0 < K; k0 += 16) {
#pragma unroll
    for (int r = 0; r < 4; ++r) {
      int li = t + 256 * r;
      int m = li >> 4, ka = li & 15;
      float va = 0.0f;
      if (m0 + m < M) va = A[(size_t)(m0 + m) * lda + (k0 + ka)];
      As[ka][m] = va;
      int n = li & 63, kb = li >> 6;
      float vb = 0.0f;
      if (n0 + n < N) vb = B[(size_t)(k0 + kb) * ldb + (n0 + n)];
      Bs[kb][n] = vb;
    }
    __syncthreads();
#pragma unroll
    for (int kk = 0; kk < 16; ++kk) {
      float4 av = *(const float4*)&As[kk][ty * 4];
      float4 bv = *(const float4*)&Bs[kk][tx * 4];
      float a_[4] = {av.x, av.y, av.z, av.w};
      float b_[4] = {bv.x, bv.y, bv.z, bv.w};
#pragma unroll
      for (int i = 0; i < 4; ++i)
#pragma unroll
        for (int j = 0; j < 4; ++j) acc[i][j] = fmaf(a_[i], b_[j], acc[i][j]);
    }
    __syncthreads();
  }
#pragma unroll
  for (int i = 0; i < 4; ++i) {
    int m = m0 + ty * 4 + i;
    if (m >= M) continue;
#pragma unroll
    for (int j = 0; j < 4; ++j) {
      int n = n0 + tx * 4 + j;
      if (n >= N) continue;
      float v = acc[i][j] + bias[n];
      if (EPI == EP_RELU) v = fmaxf(v, 0.0f);
      C[(size_t)m * ldc + n] = v;
    }
  }
}

static void gemm32(hipStream_t st, int EPI,
                   const float* A, int lda, const float* B, int ldb,
                   float* C, int ldc, const float* bias, int M, int N, int K)
{
  dim3 grid((M + 63) / 64, (N + 63) / 64), blk(256);
  if (EPI == EP_RELU) gemm_k<EP_RELU><<<grid, blk, 0, st>>>(A, lda, B, ldb, C, ldc, bias, M, N, K);
  else                gemm_k<EP_LIN><<<grid, blk, 0, st>>>(A, lda, B, ldb, C, ldc, bias, M, N, K);
}

// ================= split-bf16 MFMA GEMM ========================================
// A: hi plane at A, lo at A+aOff, [rows][lda] bf16. B per batch (B0/B1 selected
// by m0 >= bRow), hi/lo planes offset bOff, [N][ldb] bf16 (pre-transposed).
// acc = Ah*Bh + Ah*Bl + Al*Bh.
enum { ME_RELU = 0, ME_SCALE = 1, ME_SIG = 2, ME_Y = 3, ME_SOFT = 4, ME_XP = 5, ME_SMAT = 6 };

template <int EPI>
__global__ __launch_bounds__(256) void mgemm_k(
    const bf16* __restrict__ A, int lda, size_t aOff,
    const bf16* __restrict__ B0, const bf16* __restrict__ B1, int ldb, size_t bOff,
    void* __restrict__ Cv, int ldc, size_t cOff,
    bf16* __restrict__ Zp, size_t zOff,
    const float* __restrict__ bias,
    const float* __restrict__ E1, const float* __restrict__ E2, int lde,
    const float* __restrict__ cptr, int bRow, int Rc, int r0, int N, int K)
{
  __shared__ char As[2][8192];   // [hi/lo][128 rows][32 k] bf16
  __shared__ char Bs[2][8192];
  const int t = threadIdx.x;
  const int lane = t & 63, wv = t >> 6;
  const int wr = wv >> 1, wc = wv & 1;
  const int m0 = blockIdx.x * 128, n0 = blockIdx.y * 128;
  const int nb = (m0 >= bRow) ? 1 : 0;
  const bf16* __restrict__ Bt = nb ? B1 : B0;
  const int row16 = lane & 15, kg = lane >> 4;
  const int grow = t >> 2;
  const int gcol = (t & 3) * 8;
  f32x4 acc[4][4];
#pragma unroll
  for (int i = 0; i < 4; ++i)
#pragma unroll
    for (int j = 0; j < 4; ++j) { acc[i][j][0] = 0.f; acc[i][j][1] = 0.f; acc[i][j][2] = 0.f; acc[i][j][3] = 0.f; }

  for (int k0 = 0; k0 < K; k0 += 32) {
#pragma unroll
    for (int h = 0; h < 2; ++h) {
#pragma unroll
      for (int i = 0; i < 2; ++i) {
        const bf16* ga = A + h * aOff + (size_t)(m0 + i * 64 + grow) * lda + k0 + gcol;
        __builtin_amdgcn_global_load_lds(
            (const __attribute__((address_space(1))) void*)ga,
            (__attribute__((address_space(3))) void*)(As[h] + i * 4096 + wv * 1024), 16, 0, 0);
        const bf16* gb = Bt + h * bOff + (size_t)(n0 + i * 64 + grow) * ldb + k0 + gcol;
        __builtin_amdgcn_global_load_lds(
            (const __attribute__((address_space(1))) void*)gb,
            (__attribute__((address_space(3))) void*)(Bs[h] + i * 4096 + wv * 1024), 16, 0, 0);
      }
    }
    __syncthreads();
    short8v ah[4], al[4], bh[4], bl[4];
#pragma unroll
    for (int mi = 0; mi < 4; ++mi) {
      int o = (wr * 64 + mi * 16 + row16) * 64 + kg * 16;
      ah[mi] = *(const short8v*)(As[0] + o);
      al[mi] = *(const short8v*)(As[1] + o);
    }
#pragma unroll
    for (int ni = 0; ni < 4; ++ni) {
      int o = (wc * 64 + ni * 16 + row16) * 64 + kg * 16;
      bh[ni] = *(const short8v*)(Bs[0] + o);
      bl[ni] = *(const short8v*)(Bs[1] + o);
    }
#pragma unroll
    for (int mi = 0; mi < 4; ++mi)
#pragma unroll
      for (int ni = 0; ni < 4; ++ni) {
        acc[mi][ni] = __builtin_amdgcn_mfma_f32_16x16x32_bf16(ah[mi], bl[ni], acc[mi][ni], 0, 0, 0);
        acc[mi][ni] = __builtin_amdgcn_mfma_f32_16x16x32_bf16(al[mi], bh[ni], acc[mi][ni], 0, 0, 0);
        acc[mi][ni] = __builtin_amdgcn_mfma_f32_16x16x32_bf16(ah[mi], bh[ni], acc[mi][ni], 0, 0, 0);
      }
    __syncthreads();
  }

  float invc = 1.0f;
  if (EPI == ME_SCALE || EPI == ME_SOFT || EPI == ME_SMAT) invc = 1.0f / cptr[0];
  bf16* Cb = (bf16*)Cv;
  float* Cf = (float*)Cv;
#pragma unroll
  for (int ni = 0; ni < 4; ++ni) {
    int col = n0 + wc * 64 + ni * 16 + row16;
    const bool colok = col < N;
    float bv = 0.0f;
    if ((EPI == ME_RELU || EPI == ME_SCALE || EPI == ME_SIG) && colok) bv = bias[col];
#pragma unroll
    for (int mi = 0; mi < 4; ++mi) {
      int rowb = m0 + wr * 64 + mi * 16 + kg * 4;
#pragma unroll
      for (int r = 0; r < 4; ++r) {
        int row = rowb + r;
        float v = acc[mi][ni][r];
        if (EPI == ME_RELU) {
          if (colok) {
            float o = fmaxf(v + bv, 0.0f);
            bf16 h, l; split2(o, h, l);
            size_t ci = (size_t)row * ldc + col;
            Cb[ci] = h; Cb[ci + cOff] = l;
          }
        } else if (EPI == ME_SCALE) {
          if (colok) Cf[(size_t)row * ldc + col] = (v + bv) * invc;
        } else if (EPI == ME_SIG) {
          if (colok) {
            int rl = row - nb * bRow;
            if (rl < Rc && rl >= 0)
              Cf[(size_t)col * NLR + (size_t)nb * L_LOC + r0 + rl] = sigf(v + bv);
          }
        } else if (EPI == ME_Y) {
          if (colok) {
            size_t e = (size_t)row * lde + col;
            Cf[(size_t)row * ldc + col] = v;
            float o = softf(v, E1[e]);
            bf16 h, l; split2(o, h, l);
            size_t zi = (size_t)row * 640 + col;
            Zp[zi] = h; Zp[zi + zOff] = l;
          }
        } else if (EPI == ME_SOFT) {
          if (colok) {
            size_t e = (size_t)row * lde + col;
            float o = softf(v + E1[e] * invc, E2[e]);
            bf16 h, l; split2(o, h, l);
            size_t ci = (size_t)row * ldc + col;
            Cb[ci] = h; Cb[ci + cOff] = l;
          }
        } else if (EPI == ME_XP) {
          int rl = row - nb * bRow;
          if (colok && rl < Rc && rl >= 0) {
            size_t g = (size_t)col * NLR + (size_t)nb * L_LOC + r0 + rl;
            Cf[g] = fminf(fmaxf(v, 0.0f), 1.0f) * E1[g];
          }
        } else { // ME_SMAT
          if (row < Rc && colok)
            Cf[(size_t)row * ldc + col] = (row == col ? 1.0f : 0.0f) - v * invc;
        }
      }
    }
  }
}

static void mgemm(hipStream_t st, int EPI,
                  const bf16* A, int lda, size_t aOff,
                  const bf16* B0, const bf16* B1, int ldb, size_t bOff,
                  void* C, int ldc, size_t cOff,
                  bf16* Zp, size_t zOff,
                  const float* bias, const float* E1, const float* E2, int lde,
                  const float* cptr, int bRow, int Rc, int r0,
                  int Mp, int N, int K)
{
  dim3 grid(Mp / 128, (N + 127) / 128), blk(256);
#define MG(ep) mgemm_k<ep><<<grid, blk, 0, st>>>(A, lda, aOff, B0, B1, ldb, bOff, C, ldc, cOff, Zp, zOff, bias, E1, E2, lde, cptr, bRow, Rc, r0, N, K)
  switch (EPI) {
    case ME_RELU:  MG(ME_RELU); break;
    case ME_SCALE: MG(ME_SCALE); break;
    case ME_SIG:   MG(ME_SIG); break;
    case ME_Y:     MG(ME_Y); break;
    case ME_SOFT:  MG(ME_SOFT); break;
    case ME_XP:    MG(ME_XP); break;
    case ME_SMAT:  MG(ME_SMAT); break;
  }
#undef MG
}

// ================= small kernels ==============================================
// all 15 weight transposes in one launch
struct WTable {
  const float* src[15];
  bf16* dst[15];
  int K[15], N[15], Kp[15], Np[15];
  int base[16];
};

__global__ void wtransall_k(WTable w) {
  int idx = blockIdx.x * 256 + threadIdx.x;
  if (idx >= w.base[15]) return;
  int s = 0;
  while (s < 14 && idx >= w.base[s + 1]) ++s;
  int li = idx - w.base[s];
  int Kp = w.Kp[s];
  int n = li / Kp, k = li - n * Kp;
  float v = (n < w.N[s] && k < w.K[s]) ? w.src[s][(size_t)k * w.N[s] + n] : 0.0f;
  bf16 h, l; split2(v, h, l);
  w.dst[s][li] = h;
  w.dst[s][li + (size_t)w.Np[s] * Kp] = l;
}

// Dcat fp32 [2][256][624] -> Db [n][2pl][256][640] and DbT [n][2pl][640][256]
__global__ void dcatconv_k(const float* __restrict__ Dc, bf16* __restrict__ Db,
                           bf16* __restrict__ DbT) {
  int idx = blockIdx.x * 256 + threadIdx.x;   // 2*256*640
  if (idx >= 327680) return;
  int n = idx / 163840, r = idx - n * 163840;
  int p = r / 640, a = r - p * 640;
  float v = (a < 624) ? Dc[(size_t)n * 159744 + p * 624 + a] : 0.0f;
  bf16 h, l; split2(v, h, l);
  size_t base = (size_t)n * 327680;
  Db[base + p * 640 + a] = h;
  Db[base + 163840 + p * 640 + a] = l;
  DbT[base + (size_t)a * 256 + p] = h;
  DbT[base + 163840 + (size_t)a * 256 + p] = l;
}

// S fp32 [2][624][624] -> Sb [n][2pl][640][640] zero-padded
__global__ void sconv_k(const float* __restrict__ Sf, bf16* __restrict__ Sb) {
  int idx = blockIdx.x * 256 + threadIdx.x;   // 2*640*640
  if (idx >= 819200) return;
  int n = idx / 409600, r = idx - n * 409600;
  int i = r / 640, j = r - i * 640;
  float v = (i < 624 && j < 624) ? Sf[(size_t)n * 389376 + i * 624 + j] : 0.0f;
  bf16 h, l; split2(v, h, l);
  size_t base = (size_t)n * 819200;
  Sb[base + r] = h; Sb[base + 409600 + r] = l;
}

// unfold for both batches into the stacked chunk buffer
__global__ void unfold_k(const float* __restrict__ img, bf16* __restrict__ uf,
                         int r0, int Rc, int bRowc, size_t pOff) {
  int bi = blockIdx.x;               // 0..2*Rc-1
  int nb = bi >= Rc;
  int rl = nb ? bi - Rc : bi;
  int row = nb * bRowc + rl;
  int p = threadIdx.x;
  int l = r0 + rl;
  int i0 = l / 113, j0 = l - i0 * 113;
  float v = img[nb * 16384 + (i0 + (p >> 4)) * 128 + j0 + (p & 15)];
  bf16 h, lo; split2(v, h, lo);
  size_t o = (size_t)row * 256 + p;
  uf[o] = h; uf[o + pOff] = lo;
}

__global__ void ext_k(const float* __restrict__ x, float* __restrict__ ext) {
  int idx = blockIdx.x * 256 + threadIdx.x;  // 2*112*256
  int p = idx & 255;
  int t2 = idx >> 8;
  int e = t2 % 112, n = t2 / 112;
  int l1 = 2 * e;
  int i1 = l1 / 15, j1 = l1 % 15;
  ext[idx] = x[n * 16384 + (8 * i1 + (p >> 4)) * 128 + 8 * j1 + (p & 15)];
}

__global__ void rownorm_k(float* sd) {
  int r = blockIdx.x * 64 + threadIdx.x;
  if (r >= 224) return;
  float s = 0.0f;
  for (int i = 0; i < 256; ++i) { float v = sd[r * 256 + i]; s += v * v; }
  float sc = 1.0f / fmaxf(sqrtf(s), 1e-12f);
  for (int i = 0; i < 256; ++i) sd[r * 256 + i] *= sc;
}

// fused CBAM: channel mean/max -> shared MLP -> channel att -> spatial att
__global__ __launch_bounds__(1024) void cbam_k(
    const float* __restrict__ sd, const float* __restrict__ w1,
    const float* __restrict__ w2, const float* __restrict__ saw,
    float* __restrict__ Dcat)
{
  __shared__ float mv[512], xv[512], hm[1024], hx[1024], ca[512];
  __shared__ float smean[224], smax[224];
  const int t = threadIdx.x;
  if (t < 512) {
    int n = t >> 8, ch = t & 255;
    float s = 0.0f, m = -INFINITY;
    for (int e = 0; e < 112; ++e) {
      float v = sd[(n * 112 + e) * 256 + ch];
      s += v; m = fmaxf(m, v);
    }
    mv[t] = s * (1.0f / 112.0f);
    xv[t] = m;
  }
  __syncthreads();
  {
    int n = t >> 9, o = t & 511;
    float sm = 0.0f, sx = 0.0f;
    for (int i = 0; i < 256; ++i) {
      float w = w1[i * 512 + o];
      sm += mv[n * 256 + i] * w;
      sx += xv[n * 256 + i] * w;
    }
    hm[t] = fmaxf(sm, 0.0f);
    hx[t] = fmaxf(sx, 0.0f);
  }
  __syncthreads();
  if (t < 512) {
    int n = t >> 8, ch = t & 255;
    float s = 0.0f;
    for (int o = 0; o < 512; ++o) s += (hm[n * 512 + o] + hx[n * 512 + o]) * w2[o * 256 + ch];
    ca[t] = sigf(s);
  }
  __syncthreads();
  if (t < 224) {
    int n = t / 112, s = t % 112;
    float sum = 0.0f, mx = -INFINITY;
    for (int ch = 0; ch < 256; ++ch) {
      float v = sd[(n * 112 + s) * 256 + ch] * ca[n * 256 + ch];
      Dcat[(size_t)n * 159744 + ch * 624 + 512 + s] = v;
      sum += v; mx = fmaxf(mx, v);
    }
    smean[t] = sum * (1.0f / 256.0f);
    smax[t] = mx;
  }
  __syncthreads();
  if (t < 224) {
    int n = t / 112, s = t % 112;
    int h = s / 14, w = s % 14;
    float acc = 0.0f;
    for (int dh = 0; dh < 7; ++dh) {
      int hh = h + dh - 3; if (hh < 0 || hh >= 8) continue;
      for (int dw = 0; dw < 7; ++dw) {
        int ww = w + dw - 3; if (ww < 0 || ww >= 14) continue;
        int sp = hh * 14 + ww;
        acc += smean[n * 112 + sp] * saw[dh * 7 + dw] + smax[n * 112 + sp] * saw[49 + dh * 7 + dw];
      }
    }
    float sg = sigf(acc);
    for (int ch = 0; ch < 256; ++ch) Dcat[(size_t)n * 159744 + ch * 624 + 512 + s] *= sg;
  }
}

__global__ void dictfill_k(const float* __restrict__ Dict, float* __restrict__ Dcat) {
  int idx = blockIdx.x * 256 + threadIdx.x;  // 2*256*512
  if (idx >= 262144) return;
  int n = idx / 131072, r = idx % 131072;
  int p = r >> 9, a = r & 511;
  Dcat[(size_t)n * 159744 + p * 624 + a] = Dict[r];
}

// overlap-add fold + divide; xpT/wgT are [256 patch][NLR row] (coalesced reads)
__global__ void folddiv_k(const float* __restrict__ xpT, const float* __restrict__ wgT,
                          float* __restrict__ out) {
  int idx = blockIdx.x * 256 + threadIdx.x;
  if (idx >= 32768) return;
  int n = idx >> 14, rem = idx & 16383;
  int i = rem >> 7, j = rem & 127;
  float num = 0.0f, den = 0.0f;
  int kh0 = (i - 112 > 0) ? i - 112 : 0;
  int kh1 = (i < 15) ? i : 15;
  int kw0 = (j - 112 > 0) ? j - 112 : 0;
  int kw1 = (j < 15) ? j : 15;
  for (int kh = kh0; kh <= kh1; ++kh)
    for (int kw = kw0; kw <= kw1; ++kw) {
      int l = (i - kh) * 113 + (j - kw);
      size_t base = (size_t)(kh * 16 + kw) * NLR + (size_t)n * L_LOC + l;
      num += xpT[base];
      den += wgT[base];
    }
  out[idx] = num / den;
}

// ================= host orchestration ==========================================
struct Bufs {
  float *xp, *wg, *Dcat_f, *S_f, *ext, *sb1, *sb2, *sd, *res;
  bf16 *Db, *DbT, *Sb;
  bf16 *uf, *h1, *h2, *z, *zn;
  float *thr, *y;
  size_t ufO, h1O, h2O, zO;
  int R;
};

static void run_stage(hipStream_t st, const float* const* in, const float* img,
                      float* outimg, int pd0, int lam0,
                      bf16* const* WtPd, bf16* const* WtLam, bf16* const* WtW,
                      const Bufs& b)
{
  const float* cptr = in[2];
  // --- adaptive dictionary pipeline ---
  ext_k<<<dim3(224), dim3(256), 0, st>>>(img, b.ext);
  gemm32(st, EP_RELU, b.ext, 256, in[3], 512, b.sb1, 512, in[4], 224, 512, 256);
  gemm32(st, EP_RELU, b.sb1, 512, in[5], 1024, b.sb2, 1024, in[6], 224, 1024, 512);
  gemm32(st, EP_RELU, b.sb2, 1024, in[7], 512, b.sb1, 512, in[8], 224, 512, 1024);
  gemm32(st, EP_LIN, b.sb1, 512, in[9], 256, b.sd, 256, in[10], 224, 256, 512);
  rownorm_k<<<dim3(4), dim3(64), 0, st>>>(b.sd);
  cbam_k<<<dim3(1), dim3(1024), 0, st>>>(b.sd, in[41], in[42], in[43], b.Dcat_f);
  dictfill_k<<<dim3(1024), dim3(256), 0, st>>>(in[1], b.Dcat_f);
  dcatconv_k<<<dim3(1280), dim3(256), 0, st>>>(b.Dcat_f, b.Db, b.DbT);
  // --- S = I - D^T D / c via split-bf16 MFMA ---
  for (int n = 0; n < NB; ++n) {
    const bf16* Dt = b.DbT + (size_t)n * 327680;
    mgemm(st, ME_SMAT, Dt, 256, 163840, Dt, Dt, 256, 163840,
          b.S_f + (size_t)n * 389376, 624, 0, 0, 0,
          0, 0, 0, 0, cptr, 1 << 30, 624, 0, 640, 624, 256);
  }
  sconv_k<<<dim3(3200), dim3(256), 0, st>>>(b.S_f, b.Sb);

  // --- stacked both-batch chunks ---
  for (int r0 = 0; r0 < L_LOC; r0 += b.R) {
    int Rc = L_LOC - r0; if (Rc > b.R) Rc = b.R;
    int bRowc = ((Rc + 127) / 128) * 128;
    int Mp = 2 * bRowc;
    unfold_k<<<dim3(2 * Rc), dim3(256), 0, st>>>(img, b.uf, r0, Rc, bRowc, b.ufO);
    // pd MLP -> thr[:, :512]
    mgemm(st, ME_RELU, b.uf, 256, b.ufO, WtPd[0], WtPd[0], 256, 1024 * 256, b.h1, 1024, b.h1O,
          0, 0, in[pd0 + 1], 0, 0, 0, cptr, bRowc, Rc, r0, Mp, 1024, 256);
    mgemm(st, ME_RELU, b.h1, 1024, b.h1O, WtPd[1], WtPd[1], 1024, 512 * 1024, b.h2, 512, b.h2O,
          0, 0, in[pd0 + 3], 0, 0, 0, cptr, bRowc, Rc, r0, Mp, 512, 1024);
    mgemm(st, ME_SCALE, b.h2, 512, b.h2O, WtPd[2], WtPd[2], 512, 512 * 512, b.thr, 640, 0,
          0, 0, in[pd0 + 5], 0, 0, 0, cptr, bRowc, Rc, r0, Mp, 512, 512);
    // lam MLP -> thr[:, 512:624]
    mgemm(st, ME_RELU, b.uf, 256, b.ufO, WtLam[0], WtLam[0], 256, 1024 * 256, b.h1, 1024, b.h1O,
          0, 0, in[lam0 + 1], 0, 0, 0, cptr, bRowc, Rc, r0, Mp, 1024, 256);
    mgemm(st, ME_RELU, b.h1, 1024, b.h1O, WtLam[1], WtLam[1], 1024, 512 * 1024, b.h2, 512, b.h2O,
          0, 0, in[lam0 + 3], 0, 0, 0, cptr, bRowc, Rc, r0, Mp, 512, 1024);
    mgemm(st, ME_SCALE, b.h2, 512, b.h2O, WtLam[2], WtLam[2], 512, 128 * 512, b.thr + 512, 640, 0,
          0, 0, in[lam0 + 5], 0, 0, 0, cptr, bRowc, Rc, r0, Mp, 112, 512);
    // w MLP -> WgT (transposed, sigmoid)
    mgemm(st, ME_RELU, b.uf, 256, b.ufO, WtW[0], WtW[0], 256, 1024 * 256, b.h1, 1024, b.h1O,
          0, 0, in[36], 0, 0, 0, cptr, bRowc, Rc, r0, Mp, 1024, 256);
    mgemm(st, ME_RELU, b.h1, 1024, b.h1O, WtW[1], WtW[1], 1024, 512 * 1024, b.h2, 512, b.h2O,
          0, 0, in[38], 0, 0, 0, cptr, bRowc, Rc, r0, Mp, 512, 1024);
    mgemm(st, ME_SIG, b.h2, 512, b.h2O, WtW[2], WtW[2], 512, 256 * 512, b.wg, 0, 0,
          0, 0, in[40], 0, 0, 0, cptr, bRowc, Rc, r0, Mp, 256, 512);
    // y = uf @ Dcat, fused z0 = soft(y, thr)
    mgemm(st, ME_Y, b.uf, 256, b.ufO, b.DbT, b.DbT + 327680, 256, 163840, b.y, 640, 0,
          b.z, b.zO, 0, b.thr, 0, 640, cptr, bRowc, Rc, r0, Mp, 624, 256);
    // LISTA iterations
    bf16* zi = b.z; bf16* zo = b.zn;
    for (int it = 0; it < 5; ++it) {
      mgemm(st, ME_SOFT, zi, 640, b.zO, b.Sb, b.Sb + 819200, 640, 409600, zo, 640, b.zO,
            0, 0, 0, b.y, b.thr, 640, cptr, bRowc, Rc, r0, Mp, 624, 640);
      bf16* tmp = zi; zi = zo; zo = tmp;
    }
    // x_pred -> xpT (transposed, clip * Wg)
    mgemm(st, ME_XP, zi, 640, b.zO, b.Db, b.Db + 327680, 640, 163840, b.xp, 0, 0,
          0, 0, 0, b.wg, 0, 0, cptr, bRowc, Rc, r0, Mp, 256, 640);
  }
  folddiv_k<<<dim3(128), dim3(256), 0, st>>>(b.xp, b.wg, outimg);
}

extern "C" void kernel_launch(void* const* d_in, const int* in_sizes, int n_in,
                              void* d_out, int out_size, void* d_ws, size_t ws_size,
                              hipStream_t stream)
{
  (void)in_sizes; (void)n_in; (void)out_size;
  const float* const* in = (const float* const*)d_in;
  char* base = (char*)d_ws;
  size_t off = 0;
  auto allocf = [&](size_t nelem) -> float* {
    float* p = (float*)(base + off);
    off += ((nelem * 4 + 255) / 256) * 256;
    return p;
  };
  auto allocb = [&](size_t nelem) -> bf16* {   // nelem per plane, hi+lo planes
    bf16* p = (bf16*)(base + off);
    off += ((nelem * 2 * 2 + 255) / 256) * 256;
    return p;
  };
  Bufs b;
  b.xp = allocf((size_t)NLR * 256);   // transposed [256][NLR]
  b.wg = allocf((size_t)NLR * 256);   // transposed [256][NLR]
  b.Dcat_f = allocf(2 * 256 * 624);
  b.S_f = allocf(2 * 624 * 624);
  b.ext = allocf(224 * 256);
  b.sb1 = allocf(224 * 1024);
  b.sb2 = allocf(224 * 1024);
  b.sd = allocf(224 * 256);
  b.res = allocf(2 * 16384);
  b.Db = allocb(2 * 163840);
  b.DbT = allocb(2 * 163840);
  b.Sb = allocb(2 * 409600);

  // transposed split-bf16 weights (single merged launch)
  bf16 *Wa[3], *Wp[3], *Wb[3], *Wq[3], *Ww[3];
  struct WDesc { bf16** slot; int inIdx; int K, N, Kp, Np; };
  WDesc wd[15] = {
    {&Wa[0], 11, 256, 1024, 256, 1024}, {&Wa[1], 13, 1024, 512, 1024, 512}, {&Wa[2], 15, 512, 112, 512, 128},
    {&Wp[0], 17, 256, 1024, 256, 1024}, {&Wp[1], 19, 1024, 512, 1024, 512}, {&Wp[2], 21, 512, 512, 512, 512},
    {&Wb[0], 23, 256, 1024, 256, 1024}, {&Wb[1], 25, 1024, 512, 1024, 512}, {&Wb[2], 27, 512, 112, 512, 128},
    {&Wq[0], 29, 256, 1024, 256, 1024}, {&Wq[1], 31, 1024, 512, 1024, 512}, {&Wq[2], 33, 512, 512, 512, 512},
    {&Ww[0], 35, 256, 1024, 256, 1024}, {&Ww[1], 37, 1024, 512, 1024, 512}, {&Ww[2], 39, 512, 256, 512, 256},
  };
  WTable wt;
  int tot = 0;
  for (int i = 0; i < 15; ++i) {
    *wd[i].slot = allocb((size_t)wd[i].Np * wd[i].Kp);
    wt.src[i] = in[wd[i].inIdx];
    wt.dst[i] = *wd[i].slot;
    wt.K[i] = wd[i].K; wt.N[i] = wd[i].N; wt.Kp[i] = wd[i].Kp; wt.Np[i] = wd[i].Np;
    wt.base[i] = tot;
    tot += wd[i].Np * wd[i].Kp;
  }
  wt.base[15] = tot;
  wtransall_k<<<dim3((tot + 255) / 256), dim3(256), 0, stream>>>(wt);

  // chunk size (per batch-row bytes: uf 1024 + h1 4096 + h2 2048 + z 2560 +
  // zn 2560 + thr 2560 + y 2560 = 17408; chunk holds 2R rows)
  long long avail = (long long)ws_size - (long long)off - (1 << 20);
  long long perrow2 = 2LL * (17408 + 64);
  int R = 12800;
  if (avail / perrow2 < 12800) R = (int)(avail / perrow2);
  R &= ~127;
  if (R < 128) R = 128;
  b.R = R;
  size_t rows2 = (size_t)2 * R;
  b.uf = allocb(rows2 * 256);  b.ufO = rows2 * 256;
  b.h1 = allocb(rows2 * 1024); b.h1O = rows2 * 1024;
  b.h2 = allocb(rows2 * 512);  b.h2O = rows2 * 512;
  b.z = allocb(rows2 * 640);   b.zO = rows2 * 640;
  b.zn = allocb(rows2 * 640);
  b.thr = allocf(rows2 * 640);
  b.y = allocf(rows2 * 640);

  // stage 1: pd = p*(17), lam = a*(11); stage 2: pd = q*(29), lam = b*(23)
  run_stage(stream, in, in[0], b.res, 17, 11, Wp, Wa, Ww, b);
  run_stage(stream, in, b.res, (float*)d_out, 29, 23, Wq, Wb, Ww, b);
}

// Round 5
// 4508.545 us; speedup vs baseline: 3.9938x; 1.1973x over previous
//
#include <hip/hip_runtime.h>
#include <hip/hip_bf16.h>
#include <math.h>

#define L_LOC 12769              // 113*113 sliding-window positions
#define NB 2
#define NLR (NB * L_LOC)

typedef short short8v __attribute__((ext_vector_type(8)));
typedef float f32x4 __attribute__((ext_vector_type(4)));
typedef __hip_bfloat16 bf16;

__device__ __forceinline__ float softf(float x, float l) {
  float a = fmaxf(fabsf(x) - l, 0.0f);
  return x > 0.0f ? a : (x < 0.0f ? -a : 0.0f);
}
__device__ __forceinline__ float sigf(float x) { return 1.0f / (1.0f + expf(-x)); }
__device__ __forceinline__ void split2(float v, bf16& h, bf16& l) {
  h = __float2bfloat16(v);
  l = __float2bfloat16(v - __bfloat162float(h));
}

// ================= fused sd-MLP (ext + 4 layers + rownorm), 1 block/row =======
__global__ __launch_bounds__(256) void sdmlp_k(
    const float* __restrict__ img,
    const float* __restrict__ w1, const float* __restrict__ b1,
    const float* __restrict__ w2, const float* __restrict__ b2,
    const float* __restrict__ w3, const float* __restrict__ b3,
    const float* __restrict__ w4, const float* __restrict__ b4,
    float* __restrict__ sd)
{
  __shared__ float bufA[1024];
  __shared__ float bufB[1024];
  __shared__ float red[4];
  const int r = blockIdx.x;          // 0..223
  const int n = r / 112, e = r - n * 112;
  const int t = threadIdx.x;
  {  // stride-8 unfold row (ext): l1 = 2e on the 15x15 grid
    int l1 = 2 * e;
    int i1 = l1 / 15, j1 = l1 - i1 * 15;
    bufA[t] = img[n * 16384 + (8 * i1 + (t >> 4)) * 128 + 8 * j1 + (t & 15)];
  }
  __syncthreads();
  // L1: 256 -> 512, relu  (bufA -> bufB)
  {
    float a0 = b1[t], a1 = b1[t + 256];
#pragma unroll 4
    for (int k = 0; k < 256; ++k) {
      float a = bufA[k];
      a0 = fmaf(a, w1[k * 512 + t], a0);
      a1 = fmaf(a, w1[k * 512 + t + 256], a1);
    }
    bufB[t] = fmaxf(a0, 0.0f);
    bufB[t + 256] = fmaxf(a1, 0.0f);
  }
  __syncthreads();
  // L2: 512 -> 1024, relu  (bufB -> bufA)
  {
    float a0 = b2[t], a1 = b2[t + 256], a2 = b2[t + 512], a3 = b2[t + 768];
#pragma unroll 4
    for (int k = 0; k < 512; ++k) {
      float a = bufB[k];
      a0 = fmaf(a, w2[k * 1024 + t], a0);
      a1 = fmaf(a, w2[k * 1024 + t + 256], a1);
      a2 = fmaf(a, w2[k * 1024 + t + 512], a2);
      a3 = fmaf(a, w2[k * 1024 + t + 768], a3);
    }
    __syncthreads();   // bufB fully consumed before rewrite below? bufA is dest; safe
    bufA[t] = fmaxf(a0, 0.0f);
    bufA[t + 256] = fmaxf(a1, 0.0f);
    bufA[t + 512] = fmaxf(a2, 0.0f);
    bufA[t + 768] = fmaxf(a3, 0.0f);
  }
  __syncthreads();
  // L3: 1024 -> 512, relu  (bufA -> bufB)
  {
    float a0 = b3[t], a1 = b3[t + 256];
#pragma unroll 4
    for (int k = 0; k < 1024; ++k) {
      float a = bufA[k];
      a0 = fmaf(a, w3[k * 512 + t], a0);
      a1 = fmaf(a, w3[k * 512 + t + 256], a1);
    }
    __syncthreads();
    bufB[t] = fmaxf(a0, 0.0f);
    bufB[t + 256] = fmaxf(a1, 0.0f);
  }
  __syncthreads();
  // L4: 512 -> 256, linear; then rownorm
  float v = b4[t];
#pragma unroll 4
  for (int k = 0; k < 512; ++k) v = fmaf(bufB[k], w4[k * 256 + t], v);
  float ss = v * v;
#pragma unroll
  for (int o = 1; o < 64; o <<= 1) ss += __shfl_xor(ss, o);
  if ((t & 63) == 0) red[t >> 6] = ss;
  __syncthreads();
  float s = red[0] + red[1] + red[2] + red[3];
  float sc = 1.0f / fmaxf(sqrtf(s), 1e-12f);
  sd[r * 256 + t] = v * sc;
}

// ================= split-bf16 MFMA GEMM ========================================
// A: hi plane at A, lo at A+aOff, [rows][lda] bf16. B per batch (B0/B1 selected
// by m0 >= bRow), hi/lo planes offset bOff, [N][ldb] bf16 (pre-transposed).
// TERMS=3: acc = Ah*Bh + Ah*Bl + Al*Bh.  TERMS=1: acc = Ah*Bh.
enum { ME_RELU = 0, ME_SCALE = 1, ME_SIG = 2, ME_Y = 3, ME_SOFT = 4, ME_XP = 5, ME_SMAT = 6 };

template <int EPI, int TERMS>
__global__ __launch_bounds__(256) void mgemm_k(
    const bf16* __restrict__ A, int lda, size_t aOff,
    const bf16* __restrict__ B0, const bf16* __restrict__ B1, int ldb, size_t bOff,
    void* __restrict__ Cv, int ldc, size_t cOff,
    bf16* __restrict__ Zp, size_t zOff,
    const float* __restrict__ bias,
    const float* __restrict__ E1, const float* __restrict__ E2, int lde,
    const float* __restrict__ cptr, int bRow, int Rc, int r0, int N, int K)
{
  __shared__ char As[2][8192];   // [hi/lo][128 rows][32 k] bf16
  __shared__ char Bs[2][8192];
  const int t = threadIdx.x;
  const int lane = t & 63, wv = t >> 6;
  const int wr = wv >> 1, wc = wv & 1;
  const int m0 = blockIdx.x * 128, n0 = blockIdx.y * 128;
  const int nb = (m0 >= bRow) ? 1 : 0;
  const bf16* __restrict__ Bt = nb ? B1 : B0;
  const int row16 = lane & 15, kg = lane >> 4;
  const int grow = t >> 2;
  const int gcol = (t & 3) * 8;
  const int NPL = (TERMS == 3) ? 2 : 1;
  f32x4 acc[4][4];
#pragma unroll
  for (int i = 0; i < 4; ++i)
#pragma unroll
    for (int j = 0; j < 4; ++j) { acc[i][j][0] = 0.f; acc[i][j][1] = 0.f; acc[i][j][2] = 0.f; acc[i][j][3] = 0.f; }

  for (int k0 = 0; k0 < K; k0 += 32) {
#pragma unroll
    for (int h = 0; h < NPL; ++h) {
#pragma unroll
      for (int i = 0; i < 2; ++i) {
        const bf16* ga = A + h * aOff + (size_t)(m0 + i * 64 + grow) * lda + k0 + gcol;
        __builtin_amdgcn_global_load_lds(
            (const __attribute__((address_space(1))) void*)ga,
            (__attribute__((address_space(3))) void*)(As[h] + i * 4096 + wv * 1024), 16, 0, 0);
        const bf16* gb = Bt + h * bOff + (size_t)(n0 + i * 64 + grow) * ldb + k0 + gcol;
        __builtin_amdgcn_global_load_lds(
            (const __attribute__((address_space(1))) void*)gb,
            (__attribute__((address_space(3))) void*)(Bs[h] + i * 4096 + wv * 1024), 16, 0, 0);
      }
    }
    __syncthreads();
    short8v ah[4], al[4], bh[4], bl[4];
#pragma unroll
    for (int mi = 0; mi < 4; ++mi) {
      int o = (wr * 64 + mi * 16 + row16) * 64 + kg * 16;
      ah[mi] = *(const short8v*)(As[0] + o);
      if (TERMS == 3) al[mi] = *(const short8v*)(As[1] + o);
    }
#pragma unroll
    for (int ni = 0; ni < 4; ++ni) {
      int o = (wc * 64 + ni * 16 + row16) * 64 + kg * 16;
      bh[ni] = *(const short8v*)(Bs[0] + o);
      if (TERMS == 3) bl[ni] = *(const short8v*)(Bs[1] + o);
    }
#pragma unroll
    for (int mi = 0; mi < 4; ++mi)
#pragma unroll
      for (int ni = 0; ni < 4; ++ni) {
        if (TERMS == 3) {
          acc[mi][ni] = __builtin_amdgcn_mfma_f32_16x16x32_bf16(ah[mi], bl[ni], acc[mi][ni], 0, 0, 0);
          acc[mi][ni] = __builtin_amdgcn_mfma_f32_16x16x32_bf16(al[mi], bh[ni], acc[mi][ni], 0, 0, 0);
        }
        acc[mi][ni] = __builtin_amdgcn_mfma_f32_16x16x32_bf16(ah[mi], bh[ni], acc[mi][ni], 0, 0, 0);
      }
    __syncthreads();
  }

  float invc = 1.0f;
  if (EPI == ME_SCALE || EPI == ME_SOFT || EPI == ME_SMAT) invc = 1.0f / cptr[0];
  bf16* Cb = (bf16*)Cv;
  float* Cf = (float*)Cv;
#pragma unroll
  for (int ni = 0; ni < 4; ++ni) {
    int col = n0 + wc * 64 + ni * 16 + row16;
    const bool colok = col < N;
    float bv = 0.0f;
    if ((EPI == ME_RELU || EPI == ME_SCALE || EPI == ME_SIG) && colok) bv = bias[col];
#pragma unroll
    for (int mi = 0; mi < 4; ++mi) {
      int rowb = m0 + wr * 64 + mi * 16 + kg * 4;
#pragma unroll
      for (int r = 0; r < 4; ++r) {
        int row = rowb + r;
        float v = acc[mi][ni][r];
        if (EPI == ME_RELU) {
          if (colok) {
            float o = fmaxf(v + bv, 0.0f);
            bf16 h, l; split2(o, h, l);
            size_t ci = (size_t)row * ldc + col;
            Cb[ci] = h; Cb[ci + cOff] = l;
          }
        } else if (EPI == ME_SCALE) {
          if (colok) Cf[(size_t)row * ldc + col] = (v + bv) * invc;
        } else if (EPI == ME_SIG) {
          if (colok) {
            int rl = row - nb * bRow;
            if (rl < Rc && rl >= 0)
              Cf[(size_t)col * NLR + (size_t)nb * L_LOC + r0 + rl] = sigf(v + bv);
          }
        } else if (EPI == ME_Y) {
          if (colok) {
            size_t e = (size_t)row * lde + col;
            Cf[(size_t)row * ldc + col] = v;
            float o = softf(v, E1[e]);
            bf16 h, l; split2(o, h, l);
            size_t zi = (size_t)row * 640 + col;
            Zp[zi] = h; Zp[zi + zOff] = l;
          }
        } else if (EPI == ME_SOFT) {
          if (colok) {
            size_t e = (size_t)row * lde + col;
            float o = softf(v + E1[e] * invc, E2[e]);
            bf16 h, l; split2(o, h, l);
            size_t ci = (size_t)row * ldc + col;
            Cb[ci] = h; Cb[ci + cOff] = l;
          }
        } else if (EPI == ME_XP) {
          int rl = row - nb * bRow;
          if (colok && rl < Rc && rl >= 0) {
            size_t g = (size_t)col * NLR + (size_t)nb * L_LOC + r0 + rl;
            Cf[g] = fminf(fmaxf(v, 0.0f), 1.0f) * E1[g];
          }
        } else { // ME_SMAT
          if (row < Rc && colok)
            Cf[(size_t)row * ldc + col] = (row == col ? 1.0f : 0.0f) - v * invc;
        }
      }
    }
  }
}

static void mgemm(hipStream_t st, int EPI,
                  const bf16* A, int lda, size_t aOff,
                  const bf16* B0, const bf16* B1, int ldb, size_t bOff,
                  void* C, int ldc, size_t cOff,
                  bf16* Zp, size_t zOff,
                  const float* bias, const float* E1, const float* E2, int lde,
                  const float* cptr, int bRow, int Rc, int r0,
                  int Mp, int N, int K)
{
  dim3 grid(Mp / 128, (N + 127) / 128), blk(256);
#define MG(ep, tm) mgemm_k<ep, tm><<<grid, blk, 0, st>>>(A, lda, aOff, B0, B1, ldb, bOff, C, ldc, cOff, Zp, zOff, bias, E1, E2, lde, cptr, bRow, Rc, r0, N, K)
  switch (EPI) {
    case ME_RELU:  MG(ME_RELU, 1); break;   // MLP hidden layers: plain bf16
    case ME_SCALE: MG(ME_SCALE, 3); break;  // thr layers: split
    case ME_SIG:   MG(ME_SIG, 1); break;    // Wg: plain bf16
    case ME_Y:     MG(ME_Y, 3); break;
    case ME_SOFT:  MG(ME_SOFT, 3); break;
    case ME_XP:    MG(ME_XP, 3); break;
    case ME_SMAT:  MG(ME_SMAT, 3); break;
  }
#undef MG
}

// ================= small kernels ==============================================
struct WTable {
  const float* src[15];
  bf16* dst[15];
  int K[15], N[15], Kp[15], Np[15];
  int base[16];
};

__global__ void wtransall_k(WTable w) {
  int idx = blockIdx.x * 256 + threadIdx.x;
  if (idx >= w.base[15]) return;
  int s = 0;
  while (s < 14 && idx >= w.base[s + 1]) ++s;
  int li = idx - w.base[s];
  int Kp = w.Kp[s];
  int n = li / Kp, k = li - n * Kp;
  float v = (n < w.N[s] && k < w.K[s]) ? w.src[s][(size_t)k * w.N[s] + n] : 0.0f;
  bf16 h, l; split2(v, h, l);
  w.dst[s][li] = h;
  w.dst[s][li + (size_t)w.Np[s] * Kp] = l;
}

// Dict [256][512] + Dcat_f sd-part -> Db [n][2pl][256][640], DbT [n][2pl][640][256]
__global__ void dcatconv_k(const float* __restrict__ Dict, const float* __restrict__ Dc,
                           bf16* __restrict__ Db, bf16* __restrict__ DbT) {
  int idx = blockIdx.x * 256 + threadIdx.x;   // 2*256*640
  if (idx >= 327680) return;
  int n = idx / 163840, r = idx - n * 163840;
  int p = r / 640, a = r - p * 640;
  float v = 0.0f;
  if (a < 512)      v = Dict[p * 512 + a];
  else if (a < 624) v = Dc[(size_t)n * 159744 + p * 624 + a];
  bf16 h, l; split2(v, h, l);
  size_t base = (size_t)n * 327680;
  Db[base + p * 640 + a] = h;
  Db[base + 163840 + p * 640 + a] = l;
  DbT[base + (size_t)a * 256 + p] = h;
  DbT[base + 163840 + (size_t)a * 256 + p] = l;
}

// S fp32 [2][624][624] -> Sb [n][2pl][640][640] zero-padded
__global__ void sconv_k(const float* __restrict__ Sf, bf16* __restrict__ Sb) {
  int idx = blockIdx.x * 256 + threadIdx.x;   // 2*640*640
  if (idx >= 819200) return;
  int n = idx / 409600, r = idx - n * 409600;
  int i = r / 640, j = r - i * 640;
  float v = (i < 624 && j < 624) ? Sf[(size_t)n * 389376 + i * 624 + j] : 0.0f;
  bf16 h, l; split2(v, h, l);
  size_t base = (size_t)n * 819200;
  Sb[base + r] = h; Sb[base + 409600 + r] = l;
}

// unfold for both batches into the stacked chunk buffer
__global__ void unfold_k(const float* __restrict__ img, bf16* __restrict__ uf,
                         int r0, int Rc, int bRowc, size_t pOff) {
  int bi = blockIdx.x;               // 0..2*Rc-1
  int nb = bi >= Rc;
  int rl = nb ? bi - Rc : bi;
  int row = nb * bRowc + rl;
  int p = threadIdx.x;
  int l = r0 + rl;
  int i0 = l / 113, j0 = l - i0 * 113;
  float v = img[nb * 16384 + (i0 + (p >> 4)) * 128 + j0 + (p & 15)];
  bf16 h, lo; split2(v, h, lo);
  size_t o = (size_t)row * 256 + p;
  uf[o] = h; uf[o + pOff] = lo;
}

// fused CBAM: channel mean/max -> shared MLP -> channel att -> spatial att
__global__ __launch_bounds__(1024) void cbam_k(
    const float* __restrict__ sd, const float* __restrict__ w1,
    const float* __restrict__ w2, const float* __restrict__ saw,
    float* __restrict__ Dcat)
{
  __shared__ float mv[512], xv[512], hm[1024], hx[1024], ca[512];
  __shared__ float smean[224], smax[224];
  const int t = threadIdx.x;
  if (t < 512) {
    int n = t >> 8, ch = t & 255;
    float s = 0.0f, m = -INFINITY;
    for (int e = 0; e < 112; ++e) {
      float v = sd[(n * 112 + e) * 256 + ch];
      s += v; m = fmaxf(m, v);
    }
    mv[t] = s * (1.0f / 112.0f);
    xv[t] = m;
  }
  __syncthreads();
  {
    int n = t >> 9, o = t & 511;
    float sm = 0.0f, sx = 0.0f;
    for (int i = 0; i < 256; ++i) {
      float w = w1[i * 512 + o];
      sm += mv[n * 256 + i] * w;
      sx += xv[n * 256 + i] * w;
    }
    hm[t] = fmaxf(sm, 0.0f);
    hx[t] = fmaxf(sx, 0.0f);
  }
  __syncthreads();
  if (t < 512) {
    int n = t >> 8, ch = t & 255;
    float s = 0.0f;
    for (int o = 0; o < 512; ++o) s += (hm[n * 512 + o] + hx[n * 512 + o]) * w2[o * 256 + ch];
    ca[t] = sigf(s);
  }
  __syncthreads();
  if (t < 224) {
    int n = t / 112, s = t % 112;
    float sum = 0.0f, mx = -INFINITY;
    for (int ch = 0; ch < 256; ++ch) {
      float v = sd[(n * 112 + s) * 256 + ch] * ca[n * 256 + ch];
      Dcat[(size_t)n * 159744 + ch * 624 + 512 + s] = v;
      sum += v; mx = fmaxf(mx, v);
    }
    smean[t] = sum * (1.0f / 256.0f);
    smax[t] = mx;
  }
  __syncthreads();
  if (t < 224) {
    int n = t / 112, s = t % 112;
    int h = s / 14, w = s % 14;
    float acc = 0.0f;
    for (int dh = 0; dh < 7; ++dh) {
      int hh = h + dh - 3; if (hh < 0 || hh >= 8) continue;
      for (int dw = 0; dw < 7; ++dw) {
        int ww = w + dw - 3; if (ww < 0 || ww >= 14) continue;
        int sp = hh * 14 + ww;
        acc += smean[n * 112 + sp] * saw[dh * 7 + dw] + smax[n * 112 + sp] * saw[49 + dh * 7 + dw];
      }
    }
    float sg = sigf(acc);
    for (int ch = 0; ch < 256; ++ch) Dcat[(size_t)n * 159744 + ch * 624 + 512 + s] *= sg;
  }
}

// overlap-add fold + divide; xpT/wgT are [256 patch][NLR row] (coalesced reads)
__global__ void folddiv_k(const float* __restrict__ xpT, const float* __restrict__ wgT,
                          float* __restrict__ out) {
  int idx = blockIdx.x * 256 + threadIdx.x;
  if (idx >= 32768) return;
  int n = idx >> 14, rem = idx & 16383;
  int i = rem >> 7, j = rem & 127;
  float num = 0.0f, den = 0.0f;
  int kh0 = (i - 112 > 0) ? i - 112 : 0;
  int kh1 = (i < 15) ? i : 15;
  int kw0 = (j - 112 > 0) ? j - 112 : 0;
  int kw1 = (j < 15) ? j : 15;
  for (int kh = kh0; kh <= kh1; ++kh)
    for (int kw = kw0; kw <= kw1; ++kw) {
      int l = (i - kh) * 113 + (j - kw);
      size_t base = (size_t)(kh * 16 + kw) * NLR + (size_t)n * L_LOC + l;
      num += xpT[base];
      den += wgT[base];
    }
  out[idx] = num / den;
}

// ================= host orchestration ==========================================
struct Bufs {
  float *xp, *wg, *Dcat_f, *S_f, *sd, *res;
  bf16 *Db, *DbT, *Sb;
  bf16 *uf, *h1, *h2, *z, *zn;
  float *thr, *y;
  size_t ufO, h1O, h2O, zO;
  int R;
};

static void run_stage(hipStream_t st, const float* const* in, const float* img,
                      float* outimg, int pd0, int lam0,
                      bf16* const* WtPd, bf16* const* WtLam, bf16* const* WtW,
                      const Bufs& b)
{
  const float* cptr = in[2];
  // --- adaptive dictionary pipeline (fused) ---
  sdmlp_k<<<dim3(224), dim3(256), 0, st>>>(img, in[3], in[4], in[5], in[6],
                                           in[7], in[8], in[9], in[10], b.sd);
  cbam_k<<<dim3(1), dim3(1024), 0, st>>>(b.sd, in[41], in[42], in[43], b.Dcat_f);
  dcatconv_k<<<dim3(1280), dim3(256), 0, st>>>(in[1], b.Dcat_f, b.Db, b.DbT);
  // --- S = I - D^T D / c via split-bf16 MFMA ---
  for (int n = 0; n < NB; ++n) {
    const bf16* Dt = b.DbT + (size_t)n * 327680;
    mgemm(st, ME_SMAT, Dt, 256, 163840, Dt, Dt, 256, 163840,
          b.S_f + (size_t)n * 389376, 624, 0, 0, 0,
          0, 0, 0, 0, cptr, 1 << 30, 624, 0, 640, 624, 256);
  }
  sconv_k<<<dim3(3200), dim3(256), 0, st>>>(b.S_f, b.Sb);

  // --- stacked both-batch chunks ---
  for (int r0 = 0; r0 < L_LOC; r0 += b.R) {
    int Rc = L_LOC - r0; if (Rc > b.R) Rc = b.R;
    int bRowc = ((Rc + 127) / 128) * 128;
    int Mp = 2 * bRowc;
    unfold_k<<<dim3(2 * Rc), dim3(256), 0, st>>>(img, b.uf, r0, Rc, bRowc, b.ufO);
    // pd MLP -> thr[:, :512]
    mgemm(st, ME_RELU, b.uf, 256, b.ufO, WtPd[0], WtPd[0], 256, 1024 * 256, b.h1, 1024, b.h1O,
          0, 0, in[pd0 + 1], 0, 0, 0, cptr, bRowc, Rc, r0, Mp, 1024, 256);
    mgemm(st, ME_RELU, b.h1, 1024, b.h1O, WtPd[1], WtPd[1], 1024, 512 * 1024, b.h2, 512, b.h2O,
          0, 0, in[pd0 + 3], 0, 0, 0, cptr, bRowc, Rc, r0, Mp, 512, 1024);
    mgemm(st, ME_SCALE, b.h2, 512, b.h2O, WtPd[2], WtPd[2], 512, 512 * 512, b.thr, 640, 0,
          0, 0, in[pd0 + 5], 0, 0, 0, cptr, bRowc, Rc, r0, Mp, 512, 512);
    // lam MLP -> thr[:, 512:624]
    mgemm(st, ME_RELU, b.uf, 256, b.ufO, WtLam[0], WtLam[0], 256, 1024 * 256, b.h1, 1024, b.h1O,
          0, 0, in[lam0 + 1], 0, 0, 0, cptr, bRowc, Rc, r0, Mp, 1024, 256);
    mgemm(st, ME_RELU, b.h1, 1024, b.h1O, WtLam[1], WtLam[1], 1024, 512 * 1024, b.h2, 512, b.h2O,
          0, 0, in[lam0 + 3], 0, 0, 0, cptr, bRowc, Rc, r0, Mp, 512, 1024);
    mgemm(st, ME_SCALE, b.h2, 512, b.h2O, WtLam[2], WtLam[2], 512, 128 * 512, b.thr + 512, 640, 0,
          0, 0, in[lam0 + 5], 0, 0, 0, cptr, bRowc, Rc, r0, Mp, 112, 512);
    // w MLP -> WgT (transposed, sigmoid)
    mgemm(st, ME_RELU, b.uf, 256, b.ufO, WtW[0], WtW[0], 256, 1024 * 256, b.h1, 1024, b.h1O,
          0, 0, in[36], 0, 0, 0, cptr, bRowc, Rc, r0, Mp, 1024, 256);
    mgemm(st, ME_RELU, b.h1, 1024, b.h1O, WtW[1], WtW[1], 1024, 512 * 1024, b.h2, 512, b.h2O,
          0, 0, in[38], 0, 0, 0, cptr, bRowc, Rc, r0, Mp, 512, 1024);
    mgemm(st, ME_SIG, b.h2, 512, b.h2O, WtW[2], WtW[2], 512, 256 * 512, b.wg, 0, 0,
          0, 0, in[40], 0, 0, 0, cptr, bRowc, Rc, r0, Mp, 256, 512);
    // y = uf @ Dcat, fused z0 = soft(y, thr)
    mgemm(st, ME_Y, b.uf, 256, b.ufO, b.DbT, b.DbT + 327680, 256, 163840, b.y, 640, 0,
          b.z, b.zO, 0, b.thr, 0, 640, cptr, bRowc, Rc, r0, Mp, 624, 256);
    // LISTA iterations
    bf16* zi = b.z; bf16* zo = b.zn;
    for (int it = 0; it < 5; ++it) {
      mgemm(st, ME_SOFT, zi, 640, b.zO, b.Sb, b.Sb + 819200, 640, 409600, zo, 640, b.zO,
            0, 0, 0, b.y, b.thr, 640, cptr, bRowc, Rc, r0, Mp, 624, 640);
      bf16* tmp = zi; zi = zo; zo = tmp;
    }
    // x_pred -> xpT (transposed, clip * Wg)
    mgemm(st, ME_XP, zi, 640, b.zO, b.Db, b.Db + 327680, 640, 163840, b.xp, 0, 0,
          0, 0, 0, b.wg, 0, 0, cptr, bRowc, Rc, r0, Mp, 256, 640);
  }
  folddiv_k<<<dim3(128), dim3(256), 0, st>>>(b.xp, b.wg, outimg);
}

extern "C" void kernel_launch(void* const* d_in, const int* in_sizes, int n_in,
                              void* d_out, int out_size, void* d_ws, size_t ws_size,
                              hipStream_t stream)
{
  (void)in_sizes; (void)n_in; (void)out_size;
  const float* const* in = (const float* const*)d_in;
  char* base = (char*)d_ws;
  size_t off = 0;
  auto allocf = [&](size_t nelem) -> float* {
    float* p = (float*)(base + off);
    off += ((nelem * 4 + 255) / 256) * 256;
    return p;
  };
  auto allocb = [&](size_t nelem) -> bf16* {   // nelem per plane, hi+lo planes
    bf16* p = (bf16*)(base + off);
    off += ((nelem * 2 * 2 + 255) / 256) * 256;
    return p;
  };
  Bufs b;
  b.xp = allocf((size_t)NLR * 256);   // transposed [256][NLR]
  b.wg = allocf((size_t)NLR * 256);   // transposed [256][NLR]
  b.Dcat_f = allocf(2 * 256 * 624);
  b.S_f = allocf(2 * 624 * 624);
  b.sd = allocf(224 * 256);
  b.res = allocf(2 * 16384);
  b.Db = allocb(2 * 163840);
  b.DbT = allocb(2 * 163840);
  b.Sb = allocb(2 * 409600);

  // transposed split-bf16 weights (single merged launch)
  bf16 *Wa[3], *Wp[3], *Wb[3], *Wq[3], *Ww[3];
  struct WDesc { bf16** slot; int inIdx; int K, N, Kp, Np; };
  WDesc wd[15] = {
    {&Wa[0], 11, 256, 1024, 256, 1024}, {&Wa[1], 13, 1024, 512, 1024, 512}, {&Wa[2], 15, 512, 112, 512, 128},
    {&Wp[0], 17, 256, 1024, 256, 1024}, {&Wp[1], 19, 1024, 512, 1024, 512}, {&Wp[2], 21, 512, 512, 512, 512},
    {&Wb[0], 23, 256, 1024, 256, 1024}, {&Wb[1], 25, 1024, 512, 1024, 512}, {&Wb[2], 27, 512, 112, 512, 128},
    {&Wq[0], 29, 256, 1024, 256, 1024}, {&Wq[1], 31, 1024, 512, 1024, 512}, {&Wq[2], 33, 512, 512, 512, 512},
    {&Ww[0], 35, 256, 1024, 256, 1024}, {&Ww[1], 37, 1024, 512, 1024, 512}, {&Ww[2], 39, 512, 256, 512, 256},
  };
  WTable wt;
  int tot = 0;
  for (int i = 0; i < 15; ++i) {
    *wd[i].slot = allocb((size_t)wd[i].Np * wd[i].Kp);
    wt.src[i] = in[wd[i].inIdx];
    wt.dst[i] = *wd[i].slot;
    wt.K[i] = wd[i].K; wt.N[i] = wd[i].N; wt.Kp[i] = wd[i].Kp; wt.Np[i] = wd[i].Np;
    wt.base[i] = tot;
    tot += wd[i].Np * wd[i].Kp;
  }
  wt.base[15] = tot;
  wtransall_k<<<dim3((tot + 255) / 256), dim3(256), 0, stream>>>(wt);

  // chunk size (per batch-row bytes: uf 1024 + h1 4096 + h2 2048 + z 2560 +
  // zn 2560 + thr 2560 + y 2560 = 17408; chunk holds 2R rows)
  long long avail = (long long)ws_size - (long long)off - (1 << 20);
  long long perrow2 = 2LL * (17408 + 64);
  int R = 12800;
  if (avail / perrow2 < 12800) R = (int)(avail / perrow2);
  R &= ~127;
  if (R < 128) R = 128;
  b.R = R;
  size_t rows2 = (size_t)2 * R;
  b.uf = allocb(rows2 * 256);  b.ufO = rows2 * 256;
  b.h1 = allocb(rows2 * 1024); b.h1O = rows2 * 1024;
  b.h2 = allocb(rows2 * 512);  b.h2O = rows2 * 512;
  b.z = allocb(rows2 * 640);   b.zO = rows2 * 640;
  b.zn = allocb(rows2 * 640);
  b.thr = allocf(rows2 * 640);
  b.y = allocf(rows2 * 640);

  // stage 1: pd = p*(17), lam = a*(11); stage 2: pd = q*(29), lam = b*(23)
  run_stage(stream, in, in[0], b.res, 17, 11, Wp, Wa, Ww, b);
  run_stage(stream, in, b.res, (float*)d_out, 29, 23, Wq, Wb, Ww, b);
}

// Round 6
// 3260.098 us; speedup vs baseline: 5.5232x; 1.3829x over previous
//
#include <hip/hip_runtime.h>
#include <hip/hip_bf16.h>
#include <math.h>

#define L_LOC 12769              // 113*113 sliding-window positions
#define NB 2
#define NLR (NB * L_LOC)

typedef short short8v __attribute__((ext_vector_type(8)));
typedef float f32x4 __attribute__((ext_vector_type(4)));
typedef __hip_bfloat16 bf16;

__device__ __forceinline__ float softf(float x, float l) {
  float a = fmaxf(fabsf(x) - l, 0.0f);
  return x > 0.0f ? a : (x < 0.0f ? -a : 0.0f);
}
__device__ __forceinline__ float sigf(float x) { return 1.0f / (1.0f + expf(-x)); }
__device__ __forceinline__ void split2(float v, bf16& h, bf16& l) {
  h = __float2bfloat16(v);
  l = __float2bfloat16(v - __bfloat162float(h));
}

// ========== fused sd-MLP (ext + 4 layers + rownorm), 4 rows/block =============
__global__ __launch_bounds__(256) void sdmlp_k(
    const float* __restrict__ img,
    const float* __restrict__ w1, const float* __restrict__ b1,
    const float* __restrict__ w2, const float* __restrict__ b2,
    const float* __restrict__ w3, const float* __restrict__ b3,
    const float* __restrict__ w4, const float* __restrict__ b4,
    float* __restrict__ sd)
{
  __shared__ float A_[4][1024];
  __shared__ float B_[4][1024];
  __shared__ float red[4][4];    // [wave][row]
  const int r0 = blockIdx.x * 4;  // 56 blocks
  const int t = threadIdx.x;
  // ext: stride-8 unfold rows
#pragma unroll
  for (int rr = 0; rr < 4; ++rr) {
    int r = r0 + rr;
    int n = r / 112, e = r - n * 112;
    int l1 = 2 * e, i1 = l1 / 15, j1 = l1 - i1 * 15;
    A_[rr][t] = img[n * 16384 + (8 * i1 + (t >> 4)) * 128 + 8 * j1 + (t & 15)];
  }
  __syncthreads();
  // L1: 256 -> 512, relu  (A_ -> B_)
  {
    float acc[4][2];
#pragma unroll
    for (int rr = 0; rr < 4; ++rr) { acc[rr][0] = b1[t]; acc[rr][1] = b1[t + 256]; }
#pragma unroll 4
    for (int k = 0; k < 256; ++k) {
      float w0 = w1[k * 512 + t], w1v = w1[k * 512 + t + 256];
#pragma unroll
      for (int rr = 0; rr < 4; ++rr) {
        float a = A_[rr][k];
        acc[rr][0] = fmaf(a, w0, acc[rr][0]);
        acc[rr][1] = fmaf(a, w1v, acc[rr][1]);
      }
    }
#pragma unroll
    for (int rr = 0; rr < 4; ++rr) {
      B_[rr][t] = fmaxf(acc[rr][0], 0.0f);
      B_[rr][t + 256] = fmaxf(acc[rr][1], 0.0f);
    }
  }
  __syncthreads();
  // L2: 512 -> 1024, relu  (B_ -> A_)
  {
    float acc[4][4];
#pragma unroll
    for (int rr = 0; rr < 4; ++rr)
#pragma unroll
      for (int j = 0; j < 4; ++j) acc[rr][j] = b2[t + j * 256];
#pragma unroll 4
    for (int k = 0; k < 512; ++k) {
      float w0 = w2[k * 1024 + t], w1v = w2[k * 1024 + t + 256];
      float w2v = w2[k * 1024 + t + 512], w3v = w2[k * 1024 + t + 768];
#pragma unroll
      for (int rr = 0; rr < 4; ++rr) {
        float a = B_[rr][k];
        acc[rr][0] = fmaf(a, w0, acc[rr][0]);
        acc[rr][1] = fmaf(a, w1v, acc[rr][1]);
        acc[rr][2] = fmaf(a, w2v, acc[rr][2]);
        acc[rr][3] = fmaf(a, w3v, acc[rr][3]);
      }
    }
    __syncthreads();
#pragma unroll
    for (int rr = 0; rr < 4; ++rr)
#pragma unroll
      for (int j = 0; j < 4; ++j) A_[rr][t + j * 256] = fmaxf(acc[rr][j], 0.0f);
  }
  __syncthreads();
  // L3: 1024 -> 512, relu  (A_ -> B_)
  {
    float acc[4][2];
#pragma unroll
    for (int rr = 0; rr < 4; ++rr) { acc[rr][0] = b3[t]; acc[rr][1] = b3[t + 256]; }
#pragma unroll 4
    for (int k = 0; k < 1024; ++k) {
      float w0 = w3[k * 512 + t], w1v = w3[k * 512 + t + 256];
#pragma unroll
      for (int rr = 0; rr < 4; ++rr) {
        float a = A_[rr][k];
        acc[rr][0] = fmaf(a, w0, acc[rr][0]);
        acc[rr][1] = fmaf(a, w1v, acc[rr][1]);
      }
    }
    __syncthreads();
#pragma unroll
    for (int rr = 0; rr < 4; ++rr) {
      B_[rr][t] = fmaxf(acc[rr][0], 0.0f);
      B_[rr][t + 256] = fmaxf(acc[rr][1], 0.0f);
    }
  }
  __syncthreads();
  // L4: 512 -> 256, linear + rownorm
  float v[4];
#pragma unroll
  for (int rr = 0; rr < 4; ++rr) v[rr] = b4[t];
#pragma unroll 4
  for (int k = 0; k < 512; ++k) {
    float w = w4[k * 256 + t];
#pragma unroll
    for (int rr = 0; rr < 4; ++rr) v[rr] = fmaf(B_[rr][k], w, v[rr]);
  }
  float ss[4];
#pragma unroll
  for (int rr = 0; rr < 4; ++rr) ss[rr] = v[rr] * v[rr];
#pragma unroll
  for (int o = 1; o < 64; o <<= 1)
#pragma unroll
    for (int rr = 0; rr < 4; ++rr) ss[rr] += __shfl_xor(ss[rr], o);
  if ((t & 63) == 0)
#pragma unroll
    for (int rr = 0; rr < 4; ++rr) red[t >> 6][rr] = ss[rr];
  __syncthreads();
#pragma unroll
  for (int rr = 0; rr < 4; ++rr) {
    float s = red[0][rr] + red[1][rr] + red[2][rr] + red[3][rr];
    float sc = 1.0f / fmaxf(sqrtf(s), 1e-12f);
    sd[(r0 + rr) * 256 + t] = v[rr] * sc;
  }
}

// ================= split-bf16 MFMA GEMM ========================================
// A: hi plane at A, lo at A+aOff. B per batch (B0/B1 by m0>=bRow), lo at +bOff.
// TERMS=3: Ah*Bh + Ah*Bl + Al*Bh.  TERMS=2: Ah*(Bh+Bl).  TERMS=1: Ah*Bh.
enum { ME_RELU = 0, ME_SCALE = 1, ME_SIG = 2, ME_Y = 3, ME_SOFT = 4, ME_XP = 5, ME_SMAT = 6 };

template <int EPI, int TERMS, int WLO>
__global__ __launch_bounds__(256) void mgemm_k(
    const bf16* __restrict__ A, int lda, size_t aOff,
    const bf16* __restrict__ B0, const bf16* __restrict__ B1, int ldb, size_t bOff,
    void* __restrict__ Cv, int ldc, size_t cOff,
    bf16* __restrict__ Zp,
    const float* __restrict__ bias,
    const float* __restrict__ E1, const float* __restrict__ E2, int lde,
    const float* __restrict__ cptr, int bRow, int Rc, int r0, int N, int K)
{
  const int NPA = (TERMS >= 3) ? 2 : 1;
  const int NPB = (TERMS >= 2) ? 2 : 1;
  __shared__ char As[(TERMS >= 3) ? 2 : 1][8192];   // [pl][128 rows][32 k] bf16
  __shared__ char Bs[(TERMS >= 2) ? 2 : 1][8192];
  const int t = threadIdx.x;
  const int lane = t & 63, wv = t >> 6;
  const int wr = wv >> 1, wc = wv & 1;
  const int m0 = blockIdx.x * 128, n0 = blockIdx.y * 128;
  const int nb = (m0 >= bRow) ? 1 : 0;
  const bf16* __restrict__ Bt = nb ? B1 : B0;
  const int row16 = lane & 15, kg = lane >> 4;
  const int grow = t >> 2;
  const int gcol = (t & 3) * 8;
  f32x4 acc[4][4];
#pragma unroll
  for (int i = 0; i < 4; ++i)
#pragma unroll
    for (int j = 0; j < 4; ++j) { acc[i][j][0] = 0.f; acc[i][j][1] = 0.f; acc[i][j][2] = 0.f; acc[i][j][3] = 0.f; }

  for (int k0 = 0; k0 < K; k0 += 32) {
#pragma unroll
    for (int h = 0; h < NPA; ++h)
#pragma unroll
      for (int i = 0; i < 2; ++i) {
        const bf16* ga = A + h * aOff + (size_t)(m0 + i * 64 + grow) * lda + k0 + gcol;
        __builtin_amdgcn_global_load_lds(
            (const __attribute__((address_space(1))) void*)ga,
            (__attribute__((address_space(3))) void*)(As[h] + i * 4096 + wv * 1024), 16, 0, 0);
      }
#pragma unroll
    for (int h = 0; h < NPB; ++h)
#pragma unroll
      for (int i = 0; i < 2; ++i) {
        const bf16* gb = Bt + h * bOff + (size_t)(n0 + i * 64 + grow) * ldb + k0 + gcol;
        __builtin_amdgcn_global_load_lds(
            (const __attribute__((address_space(1))) void*)gb,
            (__attribute__((address_space(3))) void*)(Bs[h] + i * 4096 + wv * 1024), 16, 0, 0);
      }
    __syncthreads();
    short8v ah[4], al[4], bh[4], bl[4];
#pragma unroll
    for (int mi = 0; mi < 4; ++mi) {
      int o = (wr * 64 + mi * 16 + row16) * 64 + kg * 16;
      ah[mi] = *(const short8v*)(As[0] + o);
      if (TERMS >= 3) al[mi] = *(const short8v*)(As[NPA - 1] + o);
    }
#pragma unroll
    for (int ni = 0; ni < 4; ++ni) {
      int o = (wc * 64 + ni * 16 + row16) * 64 + kg * 16;
      bh[ni] = *(const short8v*)(Bs[0] + o);
      if (TERMS >= 2) bl[ni] = *(const short8v*)(Bs[NPB - 1] + o);
    }
#pragma unroll
    for (int mi = 0; mi < 4; ++mi)
#pragma unroll
      for (int ni = 0; ni < 4; ++ni) {
        if (TERMS >= 2)
          acc[mi][ni] = __builtin_amdgcn_mfma_f32_16x16x32_bf16(ah[mi], bl[ni], acc[mi][ni], 0, 0, 0);
        if (TERMS >= 3)
          acc[mi][ni] = __builtin_amdgcn_mfma_f32_16x16x32_bf16(al[mi], bh[ni], acc[mi][ni], 0, 0, 0);
        acc[mi][ni] = __builtin_amdgcn_mfma_f32_16x16x32_bf16(ah[mi], bh[ni], acc[mi][ni], 0, 0, 0);
      }
    __syncthreads();
  }

  float invc = 1.0f;
  if (EPI == ME_SCALE || EPI == ME_SOFT || EPI == ME_SMAT) invc = 1.0f / cptr[0];
  bf16* Cb = (bf16*)Cv;
  float* Cf = (float*)Cv;
#pragma unroll
  for (int ni = 0; ni < 4; ++ni) {
    int col = n0 + wc * 64 + ni * 16 + row16;
    const bool colok = col < N;
    float bv = 0.0f;
    if ((EPI == ME_RELU || EPI == ME_SCALE || EPI == ME_SIG) && colok) bv = bias[col];
#pragma unroll
    for (int mi = 0; mi < 4; ++mi) {
      int rowb = m0 + wr * 64 + mi * 16 + kg * 4;
#pragma unroll
      for (int r = 0; r < 4; ++r) {
        int row = rowb + r;
        float v = acc[mi][ni][r];
        if (EPI == ME_RELU) {
          if (colok) {
            float o = fmaxf(v + bv, 0.0f);
            size_t ci = (size_t)row * ldc + col;
            if (WLO) {
              bf16 h, l; split2(o, h, l);
              Cb[ci] = h; Cb[ci + cOff] = l;
            } else {
              Cb[ci] = __float2bfloat16(o);
            }
          }
        } else if (EPI == ME_SCALE) {
          if (colok) Cf[(size_t)row * ldc + col] = (v + bv) * invc;
        } else if (EPI == ME_SIG) {
          if (colok) {
            int rl = row - nb * bRow;
            if (rl < Rc && rl >= 0)
              Cf[(size_t)col * NLR + (size_t)nb * L_LOC + r0 + rl] = sigf(v + bv);
          }
        } else if (EPI == ME_Y) {
          if (colok) {
            size_t e = (size_t)row * lde + col;
            Cf[(size_t)row * ldc + col] = v;
            Zp[(size_t)row * 640 + col] = __float2bfloat16(softf(v, E1[e]));
          }
        } else if (EPI == ME_SOFT) {
          if (colok) {
            size_t e = (size_t)row * lde + col;
            Cb[(size_t)row * ldc + col] = __float2bfloat16(softf(v + E1[e] * invc, E2[e]));
          }
        } else if (EPI == ME_XP) {
          int rl = row - nb * bRow;
          if (colok && rl < Rc && rl >= 0) {
            size_t g = (size_t)col * NLR + (size_t)nb * L_LOC + r0 + rl;
            Cf[g] = fminf(fmaxf(v, 0.0f), 1.0f) * E1[g];
          }
        } else { // ME_SMAT
          if (row < Rc && colok)
            Cf[(size_t)row * ldc + col] = (row == col ? 1.0f : 0.0f) - v * invc;
        }
      }
    }
  }
}

static void mgemm(hipStream_t st, int EPI, int wlo,
                  const bf16* A, int lda, size_t aOff,
                  const bf16* B0, const bf16* B1, int ldb, size_t bOff,
                  void* C, int ldc, size_t cOff,
                  bf16* Zp,
                  const float* bias, const float* E1, const float* E2, int lde,
                  const float* cptr, int bRow, int Rc, int r0,
                  int Mp, int N, int K)
{
  dim3 grid(Mp / 128, (N + 127) / 128), blk(256);
#define MG(ep, tm, wl) mgemm_k<ep, tm, wl><<<grid, blk, 0, st>>>(A, lda, aOff, B0, B1, ldb, bOff, C, ldc, cOff, Zp, bias, E1, E2, lde, cptr, bRow, Rc, r0, N, K)
  switch (EPI) {
    case ME_RELU:  if (wlo) MG(ME_RELU, 1, 1); else MG(ME_RELU, 1, 0); break;
    case ME_SCALE: MG(ME_SCALE, 3, 0); break;
    case ME_SIG:   MG(ME_SIG, 1, 0); break;
    case ME_Y:     MG(ME_Y, 3, 0); break;
    case ME_SOFT:  MG(ME_SOFT, 2, 0); break;
    case ME_XP:    MG(ME_XP, 2, 0); break;
    case ME_SMAT:  MG(ME_SMAT, 3, 0); break;
  }
#undef MG
}

// ================= small kernels ==============================================
struct WTable {
  const float* src[15];
  bf16* dst[15];
  int K[15], N[15], Kp[15], Np[15];
  int base[16];
};

__global__ void wtransall_k(WTable w) {
  int idx = blockIdx.x * 256 + threadIdx.x;
  if (idx >= w.base[15]) return;
  int s = 0;
  while (s < 14 && idx >= w.base[s + 1]) ++s;
  int li = idx - w.base[s];
  int Kp = w.Kp[s];
  int n = li / Kp, k = li - n * Kp;
  float v = (n < w.N[s] && k < w.K[s]) ? w.src[s][(size_t)k * w.N[s] + n] : 0.0f;
  bf16 h, l; split2(v, h, l);
  w.dst[s][li] = h;
  w.dst[s][li + (size_t)w.Np[s] * Kp] = l;
}

// Dict [256][512] + Dcat_f sd-part -> Db [n][2pl][256][640], DbT [n][2pl][640][256]
__global__ void dcatconv_k(const float* __restrict__ Dict, const float* __restrict__ Dc,
                           bf16* __restrict__ Db, bf16* __restrict__ DbT) {
  int idx = blockIdx.x * 256 + threadIdx.x;   // 2*256*640
  if (idx >= 327680) return;
  int n = idx / 163840, r = idx - n * 163840;
  int p = r / 640, a = r - p * 640;
  float v = 0.0f;
  if (a < 512)      v = Dict[p * 512 + a];
  else if (a < 624) v = Dc[(size_t)n * 159744 + p * 624 + a];
  bf16 h, l; split2(v, h, l);
  size_t base = (size_t)n * 327680;
  Db[base + p * 640 + a] = h;
  Db[base + 163840 + p * 640 + a] = l;
  DbT[base + (size_t)a * 256 + p] = h;
  DbT[base + 163840 + (size_t)a * 256 + p] = l;
}

// S fp32 [2][624][624] -> Sb [n][2pl][640][640] zero-padded
__global__ void sconv_k(const float* __restrict__ Sf, bf16* __restrict__ Sb) {
  int idx = blockIdx.x * 256 + threadIdx.x;   // 2*640*640
  if (idx >= 819200) return;
  int n = idx / 409600, r = idx - n * 409600;
  int i = r / 640, j = r - i * 640;
  float v = (i < 624 && j < 624) ? Sf[(size_t)n * 389376 + i * 624 + j] : 0.0f;
  bf16 h, l; split2(v, h, l);
  size_t base = (size_t)n * 819200;
  Sb[base + r] = h; Sb[base + 409600 + r] = l;
}

// unfold for both batches into the stacked chunk buffer
__global__ void unfold_k(const float* __restrict__ img, bf16* __restrict__ uf,
                         int r0, int Rc, int bRowc, size_t pOff) {
  int bi = blockIdx.x;               // 0..2*Rc-1
  int nb = bi >= Rc;
  int rl = nb ? bi - Rc : bi;
  int row = nb * bRowc + rl;
  int p = threadIdx.x;
  int l = r0 + rl;
  int i0 = l / 113, j0 = l - i0 * 113;
  float v = img[nb * 16384 + (i0 + (p >> 4)) * 128 + j0 + (p & 15)];
  bf16 h, lo; split2(v, h, lo);
  size_t o = (size_t)row * 256 + p;
  uf[o] = h; uf[o + pOff] = lo;
}

// fused CBAM
__global__ __launch_bounds__(1024) void cbam_k(
    const float* __restrict__ sd, const float* __restrict__ w1,
    const float* __restrict__ w2, const float* __restrict__ saw,
    float* __restrict__ Dcat)
{
  __shared__ float mv[512], xv[512], hm[1024], hx[1024], ca[512];
  __shared__ float smean[224], smax[224];
  const int t = threadIdx.x;
  if (t < 512) {
    int n = t >> 8, ch = t & 255;
    float s = 0.0f, m = -INFINITY;
    for (int e = 0; e < 112; ++e) {
      float v = sd[(n * 112 + e) * 256 + ch];
      s += v; m = fmaxf(m, v);
    }
    mv[t] = s * (1.0f / 112.0f);
    xv[t] = m;
  }
  __syncthreads();
  {
    int n = t >> 9, o = t & 511;
    float sm = 0.0f, sx = 0.0f;
    for (int i = 0; i < 256; ++i) {
      float w = w1[i * 512 + o];
      sm += mv[n * 256 + i] * w;
      sx += xv[n * 256 + i] * w;
    }
    hm[t] = fmaxf(sm, 0.0f);
    hx[t] = fmaxf(sx, 0.0f);
  }
  __syncthreads();
  if (t < 512) {
    int n = t >> 8, ch = t & 255;
    float s = 0.0f;
    for (int o = 0; o < 512; ++o) s += (hm[n * 512 + o] + hx[n * 512 + o]) * w2[o * 256 + ch];
    ca[t] = sigf(s);
  }
  __syncthreads();
  if (t < 224) {
    int n = t / 112, s = t % 112;
    float sum = 0.0f, mx = -INFINITY;
    for (int ch = 0; ch < 256; ++ch) {
      float v = sd[(n * 112 + s) * 256 + ch] * ca[n * 256 + ch];
      Dcat[(size_t)n * 159744 + ch * 624 + 512 + s] = v;
      sum += v; mx = fmaxf(mx, v);
    }
    smean[t] = sum * (1.0f / 256.0f);
    smax[t] = mx;
  }
  __syncthreads();
  if (t < 224) {
    int n = t / 112, s = t % 112;
    int h = s / 14, w = s % 14;
    float acc = 0.0f;
    for (int dh = 0; dh < 7; ++dh) {
      int hh = h + dh - 3; if (hh < 0 || hh >= 8) continue;
      for (int dw = 0; dw < 7; ++dw) {
        int ww = w + dw - 3; if (ww < 0 || ww >= 14) continue;
        int sp = hh * 14 + ww;
        acc += smean[n * 112 + sp] * saw[dh * 7 + dw] + smax[n * 112 + sp] * saw[49 + dh * 7 + dw];
      }
    }
    float sg = sigf(acc);
    for (int ch = 0; ch < 256; ++ch) Dcat[(size_t)n * 159744 + ch * 624 + 512 + s] *= sg;
  }
}

// overlap-add fold + divide; xpT/wgT are [256 patch][NLR row] (coalesced reads)
__global__ void folddiv_k(const float* __restrict__ xpT, const float* __restrict__ wgT,
                          float* __restrict__ out) {
  int idx = blockIdx.x * 256 + threadIdx.x;
  if (idx >= 32768) return;
  int n = idx >> 14, rem = idx & 16383;
  int i = rem >> 7, j = rem & 127;
  float num = 0.0f, den = 0.0f;
  int kh0 = (i - 112 > 0) ? i - 112 : 0;
  int kh1 = (i < 15) ? i : 15;
  int kw0 = (j - 112 > 0) ? j - 112 : 0;
  int kw1 = (j < 15) ? j : 15;
  for (int kh = kh0; kh <= kh1; ++kh)
    for (int kw = kw0; kw <= kw1; ++kw) {
      int l = (i - kh) * 113 + (j - kw);
      size_t base = (size_t)(kh * 16 + kw) * NLR + (size_t)n * L_LOC + l;
      num += xpT[base];
      den += wgT[base];
    }
  out[idx] = num / den;
}

// ================= host orchestration ==========================================
struct Bufs {
  float *xp, *wg, *Dcat_f, *S_f, *sd, *res;
  bf16 *Db, *DbT, *Sb;
  bf16 *uf, *h1, *h2, *z, *zn;
  float *thr, *y;
  size_t ufO, h1O, h2O;
  int R;
};

static void run_stage(hipStream_t st, const float* const* in, const float* img,
                      float* outimg, int pd0, int lam0,
                      bf16* const* WtPd, bf16* const* WtLam, bf16* const* WtW,
                      const Bufs& b)
{
  const float* cptr = in[2];
  // --- adaptive dictionary pipeline (fused) ---
  sdmlp_k<<<dim3(56), dim3(256), 0, st>>>(img, in[3], in[4], in[5], in[6],
                                          in[7], in[8], in[9], in[10], b.sd);
  cbam_k<<<dim3(1), dim3(1024), 0, st>>>(b.sd, in[41], in[42], in[43], b.Dcat_f);
  dcatconv_k<<<dim3(1280), dim3(256), 0, st>>>(in[1], b.Dcat_f, b.Db, b.DbT);
  // --- S = I - D^T D / c via split-bf16 MFMA ---
  for (int n = 0; n < NB; ++n) {
    const bf16* Dt = b.DbT + (size_t)n * 327680;
    mgemm(st, ME_SMAT, 0, Dt, 256, 163840, Dt, Dt, 256, 163840,
          b.S_f + (size_t)n * 389376, 624, 0, 0,
          0, 0, 0, 0, cptr, 1 << 30, 624, 0, 640, 624, 256);
  }
  sconv_k<<<dim3(3200), dim3(256), 0, st>>>(b.S_f, b.Sb);

  // --- stacked both-batch chunks ---
  for (int r0 = 0; r0 < L_LOC; r0 += b.R) {
    int Rc = L_LOC - r0; if (Rc > b.R) Rc = b.R;
    int bRowc = ((Rc + 127) / 128) * 128;
    int Mp = 2 * bRowc;
    unfold_k<<<dim3(2 * Rc), dim3(256), 0, st>>>(img, b.uf, r0, Rc, bRowc, b.ufO);
    // pd MLP -> thr[:, :512]
    mgemm(st, ME_RELU, 0, b.uf, 256, b.ufO, WtPd[0], WtPd[0], 256, 1024 * 256, b.h1, 1024, b.h1O,
          0, in[pd0 + 1], 0, 0, 0, cptr, bRowc, Rc, r0, Mp, 1024, 256);
    mgemm(st, ME_RELU, 1, b.h1, 1024, b.h1O, WtPd[1], WtPd[1], 1024, 512 * 1024, b.h2, 512, b.h2O,
          0, in[pd0 + 3], 0, 0, 0, cptr, bRowc, Rc, r0, Mp, 512, 1024);
    mgemm(st, ME_SCALE, 0, b.h2, 512, b.h2O, WtPd[2], WtPd[2], 512, 512 * 512, b.thr, 640, 0,
          0, in[pd0 + 5], 0, 0, 0, cptr, bRowc, Rc, r0, Mp, 512, 512);
    // lam MLP -> thr[:, 512:624]
    mgemm(st, ME_RELU, 0, b.uf, 256, b.ufO, WtLam[0], WtLam[0], 256, 1024 * 256, b.h1, 1024, b.h1O,
          0, in[lam0 + 1], 0, 0, 0, cptr, bRowc, Rc, r0, Mp, 1024, 256);
    mgemm(st, ME_RELU, 1, b.h1, 1024, b.h1O, WtLam[1], WtLam[1], 1024, 512 * 1024, b.h2, 512, b.h2O,
          0, in[lam0 + 3], 0, 0, 0, cptr, bRowc, Rc, r0, Mp, 512, 1024);
    mgemm(st, ME_SCALE, 0, b.h2, 512, b.h2O, WtLam[2], WtLam[2], 512, 128 * 512, b.thr + 512, 640, 0,
          0, in[lam0 + 5], 0, 0, 0, cptr, bRowc, Rc, r0, Mp, 112, 512);
    // w MLP -> WgT (transposed, sigmoid)
    mgemm(st, ME_RELU, 0, b.uf, 256, b.ufO, WtW[0], WtW[0], 256, 1024 * 256, b.h1, 1024, b.h1O,
          0, in[36], 0, 0, 0, cptr, bRowc, Rc, r0, Mp, 1024, 256);
    mgemm(st, ME_RELU, 1, b.h1, 1024, b.h1O, WtW[1], WtW[1], 1024, 512 * 1024, b.h2, 512, b.h2O,
          0, in[38], 0, 0, 0, cptr, bRowc, Rc, r0, Mp, 512, 1024);
    mgemm(st, ME_SIG, 0, b.h2, 512, b.h2O, WtW[2], WtW[2], 512, 256 * 512, b.wg, 0, 0,
          0, in[40], 0, 0, 0, cptr, bRowc, Rc, r0, Mp, 256, 512);
    // y = uf @ Dcat, fused z0 = soft(y, thr) (z hi only)
    mgemm(st, ME_Y, 0, b.uf, 256, b.ufO, b.DbT, b.DbT + 327680, 256, 163840, b.y, 640, 0,
          b.z, 0, b.thr, 0, 640, cptr, bRowc, Rc, r0, Mp, 624, 256);
    // LISTA iterations (z hi x S split, TERMS=2)
    bf16* zi = b.z; bf16* zo = b.zn;
    for (int it = 0; it < 5; ++it) {
      mgemm(st, ME_SOFT, 0, zi, 640, 0, b.Sb, b.Sb + 819200, 640, 409600, zo, 640, 0,
            0, 0, b.y, b.thr, 640, cptr, bRowc, Rc, r0, Mp, 624, 640);
      bf16* tmp = zi; zi = zo; zo = tmp;
    }
    // x_pred -> xpT (transposed, clip * Wg), TERMS=2
    mgemm(st, ME_XP, 0, zi, 640, 0, b.Db, b.Db + 327680, 640, 163840, b.xp, 0, 0,
          0, 0, b.wg, 0, 0, cptr, bRowc, Rc, r0, Mp, 256, 640);
  }
  folddiv_k<<<dim3(128), dim3(256), 0, st>>>(b.xp, b.wg, outimg);
}

extern "C" void kernel_launch(void* const* d_in, const int* in_sizes, int n_in,
                              void* d_out, int out_size, void* d_ws, size_t ws_size,
                              hipStream_t stream)
{
  (void)in_sizes; (void)n_in; (void)out_size;
  const float* const* in = (const float* const*)d_in;
  char* base = (char*)d_ws;
  size_t off = 0;
  auto allocf = [&](size_t nelem) -> float* {
    float* p = (float*)(base + off);
    off += ((nelem * 4 + 255) / 256) * 256;
    return p;
  };
  auto allocb2 = [&](size_t nelem) -> bf16* {  // hi+lo planes
    bf16* p = (bf16*)(base + off);
    off += ((nelem * 2 * 2 + 255) / 256) * 256;
    return p;
  };
  auto allocb1 = [&](size_t nelem) -> bf16* {  // single plane
    bf16* p = (bf16*)(base + off);
    off += ((nelem * 2 + 255) / 256) * 256;
    return p;
  };
  Bufs b;
  b.xp = allocf((size_t)NLR * 256);   // transposed [256][NLR]
  b.wg = allocf((size_t)NLR * 256);   // transposed [256][NLR]
  b.Dcat_f = allocf(2 * 256 * 624);
  b.S_f = allocf(2 * 624 * 624);
  b.sd = allocf(224 * 256);
  b.res = allocf(2 * 16384);
  b.Db = allocb2(2 * 163840);
  b.DbT = allocb2(2 * 163840);
  b.Sb = allocb2(2 * 409600);

  // transposed split-bf16 weights (single merged launch)
  bf16 *Wa[3], *Wp[3], *Wb[3], *Wq[3], *Ww[3];
  struct WDesc { bf16** slot; int inIdx; int K, N, Kp, Np; };
  WDesc wd[15] = {
    {&Wa[0], 11, 256, 1024, 256, 1024}, {&Wa[1], 13, 1024, 512, 1024, 512}, {&Wa[2], 15, 512, 112, 512, 128},
    {&Wp[0], 17, 256, 1024, 256, 1024}, {&Wp[1], 19, 1024, 512, 1024, 512}, {&Wp[2], 21, 512, 512, 512, 512},
    {&Wb[0], 23, 256, 1024, 256, 1024}, {&Wb[1], 25, 1024, 512, 1024, 512}, {&Wb[2], 27, 512, 112, 512, 128},
    {&Wq[0], 29, 256, 1024, 256, 1024}, {&Wq[1], 31, 1024, 512, 1024, 512}, {&Wq[2], 33, 512, 512, 512, 512},
    {&Ww[0], 35, 256, 1024, 256, 1024}, {&Ww[1], 37, 1024, 512, 1024, 512}, {&Ww[2], 39, 512, 256, 512, 256},
  };
  WTable wt;
  int tot = 0;
  for (int i = 0; i < 15; ++i) {
    *wd[i].slot = allocb2((size_t)wd[i].Np * wd[i].Kp);
    wt.src[i] = in[wd[i].inIdx];
    wt.dst[i] = *wd[i].slot;
    wt.K[i] = wd[i].K; wt.N[i] = wd[i].N; wt.Kp[i] = wd[i].Kp; wt.Np[i] = wd[i].Np;
    wt.base[i] = tot;
    tot += wd[i].Np * wd[i].Kp;
  }
  wt.base[15] = tot;
  wtransall_k<<<dim3((tot + 255) / 256), dim3(256), 0, stream>>>(wt);

  // chunk size (per batch-row bytes: uf 1024 + h1 2048 + h2 2048 + z 1280 +
  // zn 1280 + thr 2560 + y 2560 = 12800; chunk holds 2R rows)
  long long avail = (long long)ws_size - (long long)off - (1 << 20);
  long long perrow2 = 2LL * (12800 + 64);
  int R = 12800;
  if (avail / perrow2 < 12800) R = (int)(avail / perrow2);
  R &= ~127;
  if (R < 128) R = 128;
  b.R = R;
  size_t rows2 = (size_t)2 * R;
  b.uf = allocb2(rows2 * 256);  b.ufO = rows2 * 256;
  b.h1 = allocb1(rows2 * 1024); b.h1O = 0;           // hi only (lo never read)
  b.h2 = allocb2(rows2 * 512);  b.h2O = rows2 * 512; // hi+lo (L3 TERMS=3)
  b.z = allocb1(rows2 * 640);
  b.zn = allocb1(rows2 * 640);
  b.thr = allocf(rows2 * 640);
  b.y = allocf(rows2 * 640);

  // stage 1: pd = p*(17), lam = a*(11); stage 2: pd = q*(29), lam = b*(23)
  run_stage(stream, in, in[0], b.res, 17, 11, Wp, Wa, Ww, b);
  run_stage(stream, in, b.res, (float*)d_out, 29, 23, Wq, Wb, Ww, b);
}